// Round 16
// baseline (190.632 us; speedup 1.0000x reference)
//
#include <hip/hip_runtime.h>

typedef unsigned short u16;
typedef unsigned int u32;
typedef float f32x4 __attribute__((ext_vector_type(4)));
typedef float f32x16 __attribute__((ext_vector_type(16)));
typedef short s16x8 __attribute__((ext_vector_type(8)));
typedef u16 u16x8 __attribute__((ext_vector_type(8)));
typedef u16 u16x4 __attribute__((ext_vector_type(4)));
typedef u32 u32x4 __attribute__((ext_vector_type(4)));
typedef _Float16 h16x8 __attribute__((ext_vector_type(8)));
typedef _Float16 h16x2 __attribute__((ext_vector_type(2)));

#define B_ 2
#define T_ 2048
#define H_ 16
#define D_ 1024
#define HD_ 64
#define NTOK (B_*T_)

// 0.125 (HD^-1/2) * log2(e): folded into Q projection so softmax is exp2-direct.
#define QSCALE 0.18033688011112042f

// ---------- helpers ----------
__device__ __forceinline__ u16 f2b(float f){            // fp32 -> bf16 RNE
  u32 u = __float_as_uint(f);
  return (u16)((u + 0x7fffu + ((u>>16)&1u)) >> 16);
}
__device__ __forceinline__ float b2f(u16 h){ return __uint_as_float(((u32)h)<<16); }

__device__ __forceinline__ void gload_lds16(const u16* g, u16* s){
  __builtin_amdgcn_global_load_lds((const __attribute__((address_space(1))) void*)g,
                                   (__attribute__((address_space(3))) void*)s, 16, 0, 0);
}

// Stage a [ROWS][64] 16-bit tile. LDS linear; XOR swizzle (16B unit u -> u^(r&7))
// applied on the per-lane GLOBAL source address.
template<int ROWS, int WAVES>
__device__ __forceinline__ void stage_tile(const u16* __restrict__ g, size_t ldg,
                                           u16* s, int tid){
  const int w = tid>>6, l = tid&63;
  const int rw = ROWS/WAVES;
  #pragma unroll
  for (int i=0;i<ROWS/(WAVES*8);i++){
    int r0 = w*rw + i*8;
    int r  = r0 + (l>>3);
    int u  = (l&7) ^ (r&7);
    gload_lds16(g + (size_t)r*ldg + (size_t)u*8, s + r0*64);
  }
}

// chunked read from swizzled [*][64] tile: 8 elems at 16-elem chunk ks, half hi.
__device__ __forceinline__ u16x8 rfragT(const u16* s, int r, int ks, int hi){
  int phys = (ks*2 + hi) ^ (r&7);
  return *(const u16x8*)(s + r*64 + phys*8);
}

// BK=32 bf16 tiles [ROWS][32] (8-wave staging): unit v = u^((r>>1)&3).
__device__ __forceinline__ void stage_tile32(const u16* __restrict__ g, size_t ldg,
                                             u16* s, int tid){
  const int w = tid>>6, l = tid&63;
  int r0 = w*16;
  int r  = r0 + (l>>2);
  int v  = (l&3) ^ ((r>>1)&3);
  gload_lds16(g + (size_t)r*ldg + (size_t)v*8, s + r0*32);
}
__device__ __forceinline__ u16x8 read_frag32(const u16* s, int r, int l){
  int phys = (l>>4) ^ ((r>>1)&3);
  return *(const u16x8*)(s + r*32 + phys*8);
}

__device__ __forceinline__ f32x4 mfma16_bf16(u16x8 a, u16x8 b, f32x4 c){
  return __builtin_amdgcn_mfma_f32_16x16x32_bf16(
      __builtin_bit_cast(s16x8,a), __builtin_bit_cast(s16x8,b), c, 0,0,0);
}
__device__ __forceinline__ f32x16 mfma32_f16(u16x8 a, u16x8 b, f32x16 c){
  return __builtin_amdgcn_mfma_f32_32x32x16_f16(
      __builtin_bit_cast(h16x8,a), __builtin_bit_cast(h16x8,b), c, 0,0,0);
}

__device__ __forceinline__ float ex2(float x){
#if __has_builtin(__builtin_amdgcn_exp2f)
  return __builtin_amdgcn_exp2f(x);
#else
  return exp2f(x);
#endif
}
__device__ __forceinline__ u32 pk2(float a, float b){   // two f32 -> packed f16x2 (RNE)
  u16 x = __builtin_bit_cast(u16, (_Float16)a);
  u16 y = __builtin_bit_cast(u16, (_Float16)b);
  return (u32)x | ((u32)y<<16);
}
__device__ __forceinline__ u32 pkrtz(float a, float b){ // packed cvt (v_cvt_pkrtz_f16_f32)
#if __has_builtin(__builtin_amdgcn_cvt_pkrtz)
  auto r = __builtin_amdgcn_cvt_pkrtz(a, b);   // __fp16 ext_vector(2)
  return __builtin_bit_cast(u32, r);
#else
  return pk2(a, b);
#endif
}

// ---------- split kernel: q (fp16) + 4 weight matrices ----------
__device__ __forceinline__ void split_bf4(const float* in, u16* hi, u16* lo, int i){
  f32x4 v = ((const f32x4*)in)[i];
  u16x4 h, lw;
  #pragma unroll
  for (int j=0;j<4;j++){
    u16 hb = f2b(v[j]);
    h[j] = hb;
    lw[j] = f2b(v[j] - b2f(hb));   // exact residual, then RNE
  }
  ((u16x4*)hi)[i] = h;
  ((u16x4*)lo)[i] = lw;
}
__device__ __forceinline__ void split_h4(const float* in, u16* out, int i){
  f32x4 v = ((const f32x4*)in)[i];
  u16x4 o;
  #pragma unroll
  for (int j=0;j<4;j++){
    _Float16 t = (_Float16)v[j];
    o[j] = __builtin_bit_cast(u16, t);
  }
  ((u16x4*)out)[i] = o;
}

__global__ void split_all_kernel(const float* __restrict__ q,
                                 const float* __restrict__ wq, const float* __restrict__ wk,
                                 const float* __restrict__ wv, const float* __restrict__ wo,
                                 u16* __restrict__ qh,
                                 u16* __restrict__ wqh, u16* __restrict__ wkh, u16* __restrict__ wkl,
                                 u16* __restrict__ wvh, u16* __restrict__ wvl, u16* __restrict__ woh){
  int i = blockIdx.x*256 + threadIdx.x;
  int which = blockIdx.y;
  if (which==0){ split_h4(q, qh, i); return; }
  if (i >= D_*D_/4) return;
  if (which==1)      split_h4 (wq, wqh, i);
  else if (which==2) split_bf4(wk, wkh, wkl, i);
  else if (which==3) split_bf4(wv, wvh, wvl, i);
  else               split_h4 (wo, woh, i);
}

// ---------- fp16 1-term GEMM, 32x32 MFMA: C = (A @ W^T + bias) * oscale ----------
// BM=128, BN=128, BK=64, 4 waves (wave 64x64 = 2x2 32-blocks), dbuf 2-phase.
template<int F16OUT>
__global__ __launch_bounds__(256)
void gemm1(const u16* __restrict__ Ah, const u16* __restrict__ Wh,
           const float* __restrict__ bias, void* __restrict__ Cout, float oscale)
{
  __shared__ u16 sA[2][128*64];
  __shared__ u16 sW[2][128*64];
  const int tid = threadIdx.x, l = tid&63, c = l&31, hi = l>>5, w = tid>>6;
  const int wm = w>>1, wn = w&1;
  const int bm = blockIdx.x, bn = blockIdx.y;  // (32,8)
  const u16* A0 = Ah + (size_t)bm*128*D_;
  const u16* W0 = Wh + (size_t)bn*128*D_;
  f32x16 acc[2][2] = {};   // [mb][nb]

  stage_tile<128,4>(A0, D_, sA[0], tid);
  stage_tile<128,4>(W0, D_, sW[0], tid);
  __syncthreads();
  for (int t=0; t<D_/64; ++t){
    const int cur = t&1;
    if (t+1 < D_/64){
      stage_tile<128,4>(A0 + (t+1)*64, D_, sA[cur^1], tid);
      stage_tile<128,4>(W0 + (t+1)*64, D_, sW[cur^1], tid);
    }
    #pragma unroll
    for (int kc=0;kc<4;kc++){
      u16x8 af[2], wf[2];
      af[0] = rfragT(sA[cur], wm*64 +      c, kc, hi);
      af[1] = rfragT(sA[cur], wm*64 + 32 + c, kc, hi);
      wf[0] = rfragT(sW[cur], wn*64 +      c, kc, hi);
      wf[1] = rfragT(sW[cur], wn*64 + 32 + c, kc, hi);
      #pragma unroll
      for (int mb=0;mb<2;mb++)
        #pragma unroll
        for (int nb=0;nb<2;nb++)
          acc[mb][nb] = mfma32_f16(af[mb], wf[nb], acc[mb][nb]);
    }
    __syncthreads();
  }

  #pragma unroll
  for (int nb=0;nb<2;nb++){
    int col = bn*128 + wn*64 + nb*32 + c;
    float bv = bias[col];
    #pragma unroll
    for (int mb=0;mb<2;mb++){
      #pragma unroll
      for (int r=0;r<16;r++){
        int row = bm*128 + wm*64 + mb*32 + (r&3) + 8*(r>>2) + 4*hi;
        float v = (acc[mb][nb][r] + bv) * oscale;
        if constexpr (F16OUT){
          ((_Float16*)Cout)[(size_t)row*D_ + col] = (_Float16)v;
        } else {
          ((float*)Cout)[(size_t)row*D_ + col] = v;
        }
      }
    }
  }
}

// ---------- 3-term split GEMM + fused INT4 quant-dequant ----------
// A loaded DIRECTLY global->VGPR (two dwordx4 per fm, 128B-contiguous per
// 4-lane g-group), software-pipelined one K-step ahead, split to (Ah,Al)
// in-register (hi = trunc-top-16, lo = RNE residual). Only W goes through LDS
// (dbuf 2x16KB) -> per wave-step LDS issue 8 reads vs 24 MFMA: MFMA-bound.
// 16x16 MFMA, 512 threads/8 waves, BM=BN=128, BK=32.
// grid (32,8,2): z=0 -> K row-major, z=1 -> V transposed with sigma
// (g2 = swap bit2<->bit3 of within-16 token index) baked into the layout.
__global__ __launch_bounds__(512)
void gemm3_quant_kv(const float* __restrict__ kA, const u16* __restrict__ kWh,
                    const u16* __restrict__ kWl, const float* __restrict__ kbias,
                    u16* __restrict__ kOut,
                    const float* __restrict__ vA, const u16* __restrict__ vWh,
                    const u16* __restrict__ vWl, const float* __restrict__ vbias,
                    u16* __restrict__ vOut)
{
  extern __shared__ u16 sm[];   // 34816 B: dbuf W (2x16KB) / quant repack (34816)
  const int tid = threadIdx.x, l = tid&63, w = tid>>6, l15 = l&15, g = l>>4;
  const int wm = w>>1, wn = w&1;
  const int bm = blockIdx.x, bn = blockIdx.y;   // (32, 8)
  const bool isV = blockIdx.z != 0;
  const float* Af = isV ? vA : kA;
  const u16* Wh = isV ? vWh : kWh;
  const u16* Wl = isV ? vWl : kWl;
  const float* bias = isV ? vbias : kbias;
  u16* Out = isV ? vOut : kOut;

  const u16* W0 = Wh + (size_t)bn*128*D_;
  const u16* W1 = Wl + (size_t)bn*128*D_;
  constexpr int BUF = 8192;   // u16 per buffer: Wh 4096 + Wl 4096
  f32x4 acc[2][4] = {};

  // per-lane A row pointers (fm=0: row0, fm=1: row0+16), k-base = g*8
  const float* a0p = Af + (size_t)(bm*128 + wm*32 + l15)*D_ + g*8;
  const float* a1p = a0p + (size_t)16*D_;

  auto stageW = [&](int buf, int t){
    u16* base = sm + buf*BUF;
    stage_tile32(W0 + t*32, D_, base       , tid);
    stage_tile32(W1 + t*32, D_, base + 4096, tid);
  };

  f32x4 ar[4];
  ar[0] = *(const f32x4*)(a0p);     ar[1] = *(const f32x4*)(a0p + 4);
  ar[2] = *(const f32x4*)(a1p);     ar[3] = *(const f32x4*)(a1p + 4);
  stageW(0,0);
  __syncthreads();

  for (int t=0; t<D_/32; ++t){
    const int cur = t&1;
    f32x4 nx0, nx1, nx2, nx3;
    if (t+1 < D_/32){
      nx0 = *(const f32x4*)(a0p + (t+1)*32);
      nx1 = *(const f32x4*)(a0p + (t+1)*32 + 4);
      nx2 = *(const f32x4*)(a1p + (t+1)*32);
      nx3 = *(const f32x4*)(a1p + (t+1)*32 + 4);
      stageW(cur^1, t+1);
    }
    // split current A regs -> (hi, lo) bf16 fragments
    u16x8 ahh[2], ahl[2];
    #pragma unroll
    for (int fm=0;fm<2;fm++){
      f32x4 x0 = ar[2*fm], x1 = ar[2*fm+1];
      u16x8 hh, ll;
      #pragma unroll
      for (int j=0;j<4;j++){
        u32 b0 = __float_as_uint(x0[j]);
        hh[j]   = (u16)(b0>>16);
        ll[j]   = f2b(x0[j] - __uint_as_float(b0 & 0xffff0000u));
        u32 b1 = __float_as_uint(x1[j]);
        hh[j+4] = (u16)(b1>>16);
        ll[j+4] = f2b(x1[j] - __uint_as_float(b1 & 0xffff0000u));
      }
      ahh[fm] = hh; ahl[fm] = ll;
    }
    const u16* base = sm + cur*BUF;
    u16x8 whh[4], whl[4];
    #pragma unroll
    for (int fn=0;fn<4;fn++){
      whh[fn] = read_frag32(base       , wn*64+fn*16+l15, l);
      whl[fn] = read_frag32(base + 4096, wn*64+fn*16+l15, l);
    }
    #pragma unroll
    for (int fm=0;fm<2;fm++)
      #pragma unroll
      for (int fn=0;fn<4;fn++){
        acc[fm][fn] = mfma16_bf16(ahh[fm], whh[fn], acc[fm][fn]);
        acc[fm][fn] = mfma16_bf16(ahh[fm], whl[fn], acc[fm][fn]);
        acc[fm][fn] = mfma16_bf16(ahl[fm], whh[fn], acc[fm][fn]);
      }
    __syncthreads();
    ar[0]=nx0; ar[1]=nx1; ar[2]=nx2; ar[3]=nx3;
  }

  // bias
  #pragma unroll
  for (int fn=0;fn<4;fn++){
    float bv = bias[bn*128 + wn*64 + fn*16 + l15];
    #pragma unroll
    for (int fm=0;fm<2;fm++)
      #pragma unroll
      for (int j=0;j<4;j++) acc[fm][fn][j] += bv;
  }

  // quant-dequant: wave's 64 cols = exactly one head -> per-row amax
  u16 (*sdq)[136] = (u16(*)[136])sm;   // aliases staging LDS (after final barrier)
  #pragma unroll
  for (int fm=0;fm<2;fm++)
    #pragma unroll
    for (int j=0;j<4;j++){
      float a = 0.f;
      #pragma unroll
      for (int fn=0;fn<4;fn++) a = fmaxf(a, fabsf(acc[fm][fn][j]));
      a = fmaxf(a, __shfl_xor(a,1)); a = fmaxf(a, __shfl_xor(a,2));
      a = fmaxf(a, __shfl_xor(a,4)); a = fmaxf(a, __shfl_xor(a,8));
      a = fmaxf(a, 1e-5f);
      float scale = a / 7.0f;
      int g2 = ((g&1)<<1) | (g>>1);              // sigma: swap bit2<->bit3
      int rowK = wm*32 + fm*16 + g*4  + j;
      int rowV = wm*32 + fm*16 + g2*4 + j;
      #pragma unroll
      for (int fn=0;fn<4;fn++){
        float q = rintf(acc[fm][fn][j] / scale);
        q = fminf(fmaxf(q, -8.f), 7.f);
        _Float16 dq = (_Float16)(q * scale);
        int col = wn*64 + fn*16 + l15;
        if (!isV) sdq[rowK][col] = __builtin_bit_cast(u16, dq);
        else      sdq[col][rowV] = __builtin_bit_cast(u16, dq);
      }
    }
  __syncthreads();

  if (!isV){
    int r = tid>>2, seg = tid&3;
    u16* dst = Out + (size_t)(bm*128 + r)*D_ + bn*128 + seg*32;
    #pragma unroll
    for (int i=0;i<4;i++)
      *(u16x8*)(dst + i*8) = *(const u16x8*)&sdq[r][seg*32 + i*8];
  } else {
    int cc = tid>>2, seg = tid&3;
    int hh = 2*bn + (cc>>6), dd = cc&63, b = bm>>4;
    u16* dst = Out + ((size_t)((b*H_+hh)*HD_ + dd))*T_ + (bm&15)*128 + seg*32;
    #pragma unroll
    for (int i=0;i<4;i++)
      *(u16x8*)(dst + i*8) = *(const u16x8*)&sdq[cc][seg*32 + i*8];
  }
}

// ---------- flash attention, KV-split=2, sigma-permuted V, fp16 partials ----------
// grid 1024 = 8 XCD x 4 bh x (16 qb x 2 split). Wave = 32 q-rows.
// Swapped QK^T (mfma(K,Q)=S^T): lane (c,hi) holds P[q=c][k=crow(r,hi)] in regs.
// PV: A=P in NATURAL slot order; V stored with sigma so B-frags are plain
// rfragT b128 reads. Partial O (fp16) / l (f32) to ws. (No setprio: lockstep
// regime, m190 + round-13 A/B.)
__global__ __launch_bounds__(256, 4)
void attn_kernel(const _Float16* __restrict__ Qp, const u16* __restrict__ Kdq,
                 const u16* __restrict__ Vt, u16* __restrict__ po,
                 float* __restrict__ pl)
{
  __shared__ u16 sK[2][64*64];
  __shared__ u16 sV[2][64*64];
  const int tid = threadIdx.x, l = tid&63, c = l&31, hi = l>>5, w = tid>>6;
  const int dsp = blockIdx.x;
  const int xcd = dsp & 7, slot = dsp >> 3;    // 128 slots per xcd
  const int bh = xcd*4 + (slot>>5);            // 4 bh per xcd
  const int rem = slot & 31;
  const int qb = rem >> 1, sp = rem & 1;       // q-tile, kv-split half
  const int b = bh>>4, h = bh&15;

  // Q B-frags (pre-scaled by 0.125*log2e)
  u16x8 qf[4];
  {
    const u16* qrow = (const u16*)Qp + (size_t)(b*T_ + qb*128 + w*32 + c)*D_ + h*HD_;
    #pragma unroll
    for (int ks=0;ks<4;ks++)
      qf[ks] = *(const u16x8*)(qrow + ks*16 + hi*8);
  }

  f32x16 o0 = {}, o1 = {};
  float lsp = 0.f;

  const u16* Kb = Kdq + (size_t)(b*T_ + sp*1024)*D_ + h*HD_;
  const u16* Vb = Vt  + (size_t)(bh*HD_)*T_ + sp*1024;

  stage_tile<64,4>(Kb, D_, sK[0], tid);
  stage_tile<64,4>(Vb, T_, sV[0], tid);
  __syncthreads();

  for (int kt=0; kt<16; kt++){
    const int cur = kt&1;
    if (kt+1 < 16){
      stage_tile<64,4>(Kb + (size_t)((kt+1)*64)*D_, D_, sK[cur^1], tid);
      stage_tile<64,4>(Vb + (kt+1)*64,              T_, sV[cur^1], tid);
    }
    const u16* sKc = sK[cur];
    const u16* sVc = sV[cur];

    // V B-frags: single b128 per chunk (sigma-permuted layout matches natural P)
    u16x8 vf0[4], vf1[4];
    #pragma unroll
    for (int ch=0; ch<4; ch++){
      vf0[ch] = rfragT(sVc,      c, ch, hi);
      vf1[ch] = rfragT(sVc, 32 + c, ch, hi);
    }

    #pragma unroll
    for (int kb=0;kb<2;kb++){
      f32x16 s = {};
      #pragma unroll
      for (int ks=0;ks<4;ks++){
        u16x8 kf = rfragT(sKc, kb*32 + c, ks, hi);
        s = mfma32_f16(kf, qf[ks], s);
      }
      // p = exp2(S^T); denominator: f32 tree-sum
      float p[16];
      #pragma unroll
      for (int r=0;r<16;r++) p[r] = ex2(s[r]);
      {
        float t0 = (p[0]+p[1]) + (p[2]+p[3]);
        float t1 = (p[4]+p[5]) + (p[6]+p[7]);
        float t2 = (p[8]+p[9]) + (p[10]+p[11]);
        float t3 = (p[12]+p[13]) + (p[14]+p[15]);
        lsp += (t0+t1) + (t2+t3);
      }
      // P -> fp16, natural slot order
      u32x4 pw0 = { pkrtz(p[0],p[1]),  pkrtz(p[2],p[3]),
                    pkrtz(p[4],p[5]),  pkrtz(p[6],p[7]) };
      u32x4 pw1 = { pkrtz(p[8],p[9]),  pkrtz(p[10],p[11]),
                    pkrtz(p[12],p[13]),pkrtz(p[14],p[15]) };
      u16x8 pa0 = __builtin_bit_cast(u16x8, pw0);
      u16x8 pa1 = __builtin_bit_cast(u16x8, pw1);
      o0 = mfma32_f16(pa0, vf0[kb*2+0], o0);
      o0 = mfma32_f16(pa1, vf0[kb*2+1], o0);
      o1 = mfma32_f16(pa0, vf1[kb*2+0], o1);
      o1 = mfma32_f16(pa1, vf1[kb*2+1], o1);
    }
    __syncthreads();
  }

  // partial denominator for q=c (lanes c and c+32 hold disjoint k-subsets)
  float lt = lsp + __shfl_xor(lsp, 32);
  if (hi == 0) pl[(size_t)(sp*32 + bh)*T_ + qb*128 + w*32 + c] = lt;

  u16* pob = po + ((size_t)(sp*32 + bh)*T_ + qb*128 + w*32)*HD_;
  #pragma unroll
  for (int r=0;r<16;r++){
    int crow = (r&3) + 8*(r>>2) + 4*hi;
    pob[crow*HD_ + c]      = __builtin_bit_cast(u16, (_Float16)o0[r]);
    pob[crow*HD_ + 32 + c] = __builtin_bit_cast(u16, (_Float16)o1[r]);
  }
}

// ---------- combine: Ao = (po0 + po1) / (l0 + l1), fp16, XCD-aligned ----------
__global__ __launch_bounds__(256)
void combine_kernel(const u16* __restrict__ po, const float* __restrict__ pl,
                    u16* __restrict__ Ao)
{
  const int dsp = blockIdx.x;
  const int xcd = dsp & 7, slot = dsp >> 3;     // 256 slots per xcd
  const int bh = xcd*4 + (slot>>6);             // 4 bh per xcd
  const int inner = slot & 63;
  int item = inner*256 + threadIdx.x;           // 0..16383
  int d8 = item & 7, t = item >> 3;
  size_t r0 = ((size_t)bh*T_ + t);
  size_t r1 = r0 + (size_t)32*T_;
  h16x8 a = *(const h16x8*)(po + r0*HD_ + d8*8);
  h16x8 bb = *(const h16x8*)(po + r1*HD_ + d8*8);
  float lt = pl[r0] + pl[r1];
  float rl = 1.0f / lt;
  u16x8 o;
  #pragma unroll
  for (int j=0;j<8;j++)
    o[j] = __builtin_bit_cast(u16, (_Float16)(((float)a[j] + (float)bb[j])*rl));
  int b = bh>>4, h = bh&15;
  *(u16x8*)(Ao + ((size_t)(b*T_ + t))*D_ + h*HD_ + d8*8) = o;
}

// ---------- launcher ----------
extern "C" void kernel_launch(void* const* d_in, const int* in_sizes, int n_in,
                              void* d_out, int out_size, void* d_ws, size_t ws_size,
                              hipStream_t stream)
{
  (void)in_sizes; (void)n_in; (void)out_size; (void)ws_size;
  const float* query = (const float*)d_in[0];
  const float* key   = (const float*)d_in[1];
  const float* value = (const float*)d_in[2];
  const float* Wq = (const float*)d_in[3];
  const float* bq = (const float*)d_in[4];
  const float* Wk = (const float*)d_in[5];
  const float* bk = (const float*)d_in[6];
  const float* Wv = (const float*)d_in[7];
  const float* bv = (const float*)d_in[8];
  const float* Wo = (const float*)d_in[9];
  const float* bo = (const float*)d_in[10];
  float* out = (float*)d_out;

  char* p = (char*)d_ws;
  auto take = [&](size_t n){ char* r = p; p += (n + 255) & ~(size_t)255; return r; };
  const size_t big = (size_t)NTOK*D_*2;   // 8 MB
  const size_t wsz = (size_t)D_*D_*2;     // 2 MB

  u16* q_h  = (u16*)take(big);
  u16* wq_h = (u16*)take(wsz);
  u16* wkh  = (u16*)take(wsz);  u16* wkl = (u16*)take(wsz);
  u16* wvh  = (u16*)take(wsz);  u16* wvl = (u16*)take(wsz);
  u16* wo_h = (u16*)take(wsz);
  u16*  Qp  = (u16*)take(big);   // fp16 q-projection (pre-scaled by QSCALE)
  u16*  Kdq = (u16*)take(big);   // fp16 dequantized K (row-major)
  u16*  Vtp = (u16*)take(big);   // fp16 dequantized V^T (sigma-permuted tokens)
  u16*  Ao  = (u16*)take(big);   // fp16 attention output
  u16*  po  = (u16*)take(big*2); // 16 MB fp16 attention partials (64 x 2048 x 64)
  float* pl = (float*)take((size_t)64*T_*4);   // 512 KB partial denominators

  split_all_kernel<<<dim3(NTOK*D_/4/256, 5), 256, 0, stream>>>(
      query, Wq, Wk, Wv, Wo,
      q_h, wq_h, wkh, wkl, wvh, wvl, wo_h);

  gemm1<1><<<dim3(32,8), 256, 0, stream>>>(q_h, wq_h, bq, Qp, QSCALE);

  gemm3_quant_kv<<<dim3(32,8,2), 512, 34816, stream>>>(
      key,   wkh, wkl, bk, Kdq,
      value, wvh, wvl, bv, Vtp);

  attn_kernel<<<1024, 256, 0, stream>>>((const _Float16*)Qp, Kdq, Vtp, po, pl);
  combine_kernel<<<2048, 256, 0, stream>>>(po, pl, Ao);

  gemm1<0><<<dim3(32,8), 256, 0, stream>>>(Ao, wo_h, bo, out, 1.0f);
}

// Round 17
// 174.197 us; speedup vs baseline: 1.0943x; 1.0943x over previous
//
#include <hip/hip_runtime.h>

typedef unsigned short u16;
typedef unsigned int u32;
typedef float f32x4 __attribute__((ext_vector_type(4)));
typedef float f32x16 __attribute__((ext_vector_type(16)));
typedef short s16x8 __attribute__((ext_vector_type(8)));
typedef u16 u16x8 __attribute__((ext_vector_type(8)));
typedef u16 u16x4 __attribute__((ext_vector_type(4)));
typedef u32 u32x4 __attribute__((ext_vector_type(4)));
typedef _Float16 h16x8 __attribute__((ext_vector_type(8)));
typedef _Float16 h16x2 __attribute__((ext_vector_type(2)));

#define B_ 2
#define T_ 2048
#define H_ 16
#define D_ 1024
#define HD_ 64
#define NTOK (B_*T_)

// 0.125 (HD^-1/2) * log2(e): folded into Q projection so softmax is exp2-direct.
#define QSCALE 0.18033688011112042f

// ---------- helpers ----------
__device__ __forceinline__ u16 f2b(float f){            // fp32 -> bf16 RNE
  u32 u = __float_as_uint(f);
  return (u16)((u + 0x7fffu + ((u>>16)&1u)) >> 16);
}
__device__ __forceinline__ float b2f(u16 h){ return __uint_as_float(((u32)h)<<16); }

__device__ __forceinline__ void gload_lds16(const u16* g, u16* s){
  __builtin_amdgcn_global_load_lds((const __attribute__((address_space(1))) void*)g,
                                   (__attribute__((address_space(3))) void*)s, 16, 0, 0);
}

// Stage a [ROWS][64] 16-bit tile. LDS linear; XOR swizzle (16B unit u -> u^(r&7))
// applied on the per-lane GLOBAL source address.
template<int ROWS, int WAVES>
__device__ __forceinline__ void stage_tile(const u16* __restrict__ g, size_t ldg,
                                           u16* s, int tid){
  const int w = tid>>6, l = tid&63;
  const int rw = ROWS/WAVES;
  #pragma unroll
  for (int i=0;i<ROWS/(WAVES*8);i++){
    int r0 = w*rw + i*8;
    int r  = r0 + (l>>3);
    int u  = (l&7) ^ (r&7);
    gload_lds16(g + (size_t)r*ldg + (size_t)u*8, s + r0*64);
  }
}

// chunked read from swizzled [*][64] tile: 8 elems at 16-elem chunk ks, half hi.
__device__ __forceinline__ u16x8 rfragT(const u16* s, int r, int ks, int hi){
  int phys = (ks*2 + hi) ^ (r&7);
  return *(const u16x8*)(s + r*64 + phys*8);
}

// BK=32 bf16 tiles [ROWS][32] (8-wave staging): unit v = u^((r>>1)&3).
__device__ __forceinline__ void stage_tile32(const u16* __restrict__ g, size_t ldg,
                                             u16* s, int tid){
  const int w = tid>>6, l = tid&63;
  int r0 = w*16;
  int r  = r0 + (l>>2);
  int v  = (l&3) ^ ((r>>1)&3);
  gload_lds16(g + (size_t)r*ldg + (size_t)v*8, s + r0*32);
}
__device__ __forceinline__ u16x8 read_frag32(const u16* s, int r, int l){
  int phys = (l>>4) ^ ((r>>1)&3);
  return *(const u16x8*)(s + r*32 + phys*8);
}

__device__ __forceinline__ f32x4 mfma16_bf16(u16x8 a, u16x8 b, f32x4 c){
  return __builtin_amdgcn_mfma_f32_16x16x32_bf16(
      __builtin_bit_cast(s16x8,a), __builtin_bit_cast(s16x8,b), c, 0,0,0);
}
__device__ __forceinline__ f32x16 mfma32_f16(u16x8 a, u16x8 b, f32x16 c){
  return __builtin_amdgcn_mfma_f32_32x32x16_f16(
      __builtin_bit_cast(h16x8,a), __builtin_bit_cast(h16x8,b), c, 0,0,0);
}

__device__ __forceinline__ float ex2(float x){
#if __has_builtin(__builtin_amdgcn_exp2f)
  return __builtin_amdgcn_exp2f(x);
#else
  return exp2f(x);
#endif
}
__device__ __forceinline__ u32 pk2(float a, float b){   // two f32 -> packed f16x2 (RNE)
  u16 x = __builtin_bit_cast(u16, (_Float16)a);
  u16 y = __builtin_bit_cast(u16, (_Float16)b);
  return (u32)x | ((u32)y<<16);
}
__device__ __forceinline__ u32 pkrtz(float a, float b){ // packed cvt (v_cvt_pkrtz_f16_f32)
#if __has_builtin(__builtin_amdgcn_cvt_pkrtz)
  auto r = __builtin_amdgcn_cvt_pkrtz(a, b);   // __fp16 ext_vector(2)
  return __builtin_bit_cast(u32, r);
#else
  return pk2(a, b);
#endif
}

// ---------- split kernel: q (fp16) + 4 weight matrices ----------
__device__ __forceinline__ void split_bf4(const float* in, u16* hi, u16* lo, int i){
  f32x4 v = ((const f32x4*)in)[i];
  u16x4 h, lw;
  #pragma unroll
  for (int j=0;j<4;j++){
    u16 hb = f2b(v[j]);
    h[j] = hb;
    lw[j] = f2b(v[j] - b2f(hb));   // exact residual, then RNE
  }
  ((u16x4*)hi)[i] = h;
  ((u16x4*)lo)[i] = lw;
}
__device__ __forceinline__ void split_h4(const float* in, u16* out, int i){
  f32x4 v = ((const f32x4*)in)[i];
  u16x4 o;
  #pragma unroll
  for (int j=0;j<4;j++){
    _Float16 t = (_Float16)v[j];
    o[j] = __builtin_bit_cast(u16, t);
  }
  ((u16x4*)out)[i] = o;
}

__global__ void split_all_kernel(const float* __restrict__ q,
                                 const float* __restrict__ wq, const float* __restrict__ wk,
                                 const float* __restrict__ wv, const float* __restrict__ wo,
                                 u16* __restrict__ qh,
                                 u16* __restrict__ wqh, u16* __restrict__ wkh, u16* __restrict__ wkl,
                                 u16* __restrict__ wvh, u16* __restrict__ wvl, u16* __restrict__ woh){
  int i = blockIdx.x*256 + threadIdx.x;
  int which = blockIdx.y;
  if (which==0){ split_h4(q, qh, i); return; }
  if (i >= D_*D_/4) return;
  if (which==1)      split_h4 (wq, wqh, i);
  else if (which==2) split_bf4(wk, wkh, wkl, i);
  else if (which==3) split_bf4(wv, wvh, wvl, i);
  else               split_h4 (wo, woh, i);
}

// ---------- fp16 1-term GEMM, 32x32 MFMA: C = (A @ W^T + bias) * oscale ----------
// BM=128, BN=64, BK=64, 4 waves (wave 64x32), dbuf 2-phase, 48 KB LDS ->
// 2 blocks/CU (grid 512). Grid is (bn, bm) so XCD = bn%8: W panels L2-resident.
template<int F16OUT>
__global__ __launch_bounds__(256)
void gemm1(const u16* __restrict__ Ah, const u16* __restrict__ Wh,
           const float* __restrict__ bias, void* __restrict__ Cout, float oscale)
{
  __shared__ u16 sA[2][128*64];
  __shared__ u16 sW[2][64*64];
  const int tid = threadIdx.x, l = tid&63, c = l&31, hi = l>>5, w = tid>>6;
  const int wm = w>>1, wn = w&1;
  const int bn = blockIdx.x, bm = blockIdx.y;  // (16,32): XCD = bn%8
  const u16* A0 = Ah + (size_t)bm*128*D_;
  const u16* W0 = Wh + (size_t)bn*64*D_;
  f32x16 acc[2] = {};   // [mb] (single nb)

  stage_tile<128,4>(A0, D_, sA[0], tid);
  stage_tile<64 ,4>(W0, D_, sW[0], tid);
  __syncthreads();
  for (int t=0; t<D_/64; ++t){
    const int cur = t&1;
    if (t+1 < D_/64){
      stage_tile<128,4>(A0 + (t+1)*64, D_, sA[cur^1], tid);
      stage_tile<64 ,4>(W0 + (t+1)*64, D_, sW[cur^1], tid);
    }
    #pragma unroll
    for (int kc=0;kc<4;kc++){
      u16x8 af[2], wf;
      af[0] = rfragT(sA[cur], wm*64 +      c, kc, hi);
      af[1] = rfragT(sA[cur], wm*64 + 32 + c, kc, hi);
      wf    = rfragT(sW[cur], wn*32 +      c, kc, hi);
      #pragma unroll
      for (int mb=0;mb<2;mb++)
        acc[mb] = mfma32_f16(af[mb], wf, acc[mb]);
    }
    __syncthreads();
  }

  {
    int col = bn*64 + wn*32 + c;
    float bv = bias[col];
    #pragma unroll
    for (int mb=0;mb<2;mb++){
      #pragma unroll
      for (int r=0;r<16;r++){
        int row = bm*128 + wm*64 + mb*32 + (r&3) + 8*(r>>2) + 4*hi;
        float v = (acc[mb][r] + bv) * oscale;
        if constexpr (F16OUT){
          ((_Float16*)Cout)[(size_t)row*D_ + col] = (_Float16)v;
        } else {
          ((float*)Cout)[(size_t)row*D_ + col] = v;
        }
      }
    }
  }
}

// ---------- 3-term split GEMM + fused INT4 quant-dequant (R15 structure) ----------
// A staged as RAW F32 via gload_lds (same bytes as bf16 hi+lo pair), split to
// (Ah,Al) in-register after the LDS read. 16x16 MFMA, 512 threads/8 waves,
// BM=BN=128, BK=32, dbuf. Grid (bn, bm, z): XCD = bn%8 -> each XCD's 512 KB
// W panel is L2-resident (fetched once, not 8x).
// z=0 -> K row-major; z=1 -> V transposed with sigma (g2 = swap bit2<->bit3).
__global__ __launch_bounds__(512)
void gemm3_quant_kv(const float* __restrict__ kA, const u16* __restrict__ kWh,
                    const u16* __restrict__ kWl, const float* __restrict__ kbias,
                    u16* __restrict__ kOut,
                    const float* __restrict__ vA, const u16* __restrict__ vWh,
                    const u16* __restrict__ vWl, const float* __restrict__ vbias,
                    u16* __restrict__ vOut)
{
  extern __shared__ u16 sm[];
  const int tid = threadIdx.x, l = tid&63, w = tid>>6, l15 = l&15, g = l>>4;
  const int wm = w>>1, wn = w&1;
  const int bn = blockIdx.x, bm = blockIdx.y;   // (8, 32): XCD = bn
  const bool isV = blockIdx.z != 0;
  const float* Af = isV ? vA : kA;
  const u16* Wh = isV ? vWh : kWh;
  const u16* Wl = isV ? vWl : kWl;
  const float* bias = isV ? vbias : kbias;
  u16* Out = isV ? vOut : kOut;

  const u16* A0u = (const u16*)(Af + (size_t)bm*128*D_);   // f32 rows as u16, ldg=2048
  const u16* W0 = Wh + (size_t)bn*128*D_;
  const u16* W1 = Wl + (size_t)bn*128*D_;
  // per buffer: A-f32 [128][32]f32 = 8192 u16, Wh [128][32] = 4096, Wl = 4096
  constexpr int BUF = 16384;
  f32x4 acc[2][4] = {};

  auto stage = [&](int buf, int t){
    u16* base = sm + buf*BUF;
    stage_tile<128,8>(A0u + t*64, 2048, base, tid);   // f32 tile, 128B rows
    stage_tile32(W0 + t*32, D_, base +  8192, tid);
    stage_tile32(W1 + t*32, D_, base + 12288, tid);
  };
  stage(0,0);
  __syncthreads();
  for (int t=0; t<D_/32; ++t){
    const int cur = t&1;
    if (t+1 < D_/32) stage(cur^1, t+1);
    const u16* base = sm + cur*BUF;
    // A frags: read f32, split in-register (hi=trunc16, lo=RNE residual)
    u16x8 ahh[2], ahl[2];
    #pragma unroll
    for (int fm=0;fm<2;fm++){
      int r = wm*32 + fm*16 + l15;
      int rx = r&7;
      const u16* row = base + r*64;
      f32x4 x0 = *(const f32x4*)(row + (((g*2  )^rx)*8));
      f32x4 x1 = *(const f32x4*)(row + (((g*2+1)^rx)*8));
      u16x8 hh, ll;
      #pragma unroll
      for (int j=0;j<4;j++){
        u32 b0 = __float_as_uint(x0[j]);
        hh[j]   = (u16)(b0>>16);
        ll[j]   = f2b(x0[j] - __uint_as_float(b0 & 0xffff0000u));
        u32 b1 = __float_as_uint(x1[j]);
        hh[j+4] = (u16)(b1>>16);
        ll[j+4] = f2b(x1[j] - __uint_as_float(b1 & 0xffff0000u));
      }
      ahh[fm] = hh; ahl[fm] = ll;
    }
    u16x8 whh[4], whl[4];
    #pragma unroll
    for (int fn=0;fn<4;fn++){
      whh[fn] = read_frag32(base +  8192, wn*64+fn*16+l15, l);
      whl[fn] = read_frag32(base + 12288, wn*64+fn*16+l15, l);
    }
    #pragma unroll
    for (int fm=0;fm<2;fm++)
      #pragma unroll
      for (int fn=0;fn<4;fn++){
        acc[fm][fn] = mfma16_bf16(ahh[fm], whh[fn], acc[fm][fn]);
        acc[fm][fn] = mfma16_bf16(ahh[fm], whl[fn], acc[fm][fn]);
        acc[fm][fn] = mfma16_bf16(ahl[fm], whh[fn], acc[fm][fn]);
      }
    __syncthreads();
  }

  // bias
  #pragma unroll
  for (int fn=0;fn<4;fn++){
    float bv = bias[bn*128 + wn*64 + fn*16 + l15];
    #pragma unroll
    for (int fm=0;fm<2;fm++)
      #pragma unroll
      for (int j=0;j<4;j++) acc[fm][fn][j] += bv;
  }

  // quant-dequant: wave's 64 cols = exactly one head -> per-row amax
  u16 (*sdq)[136] = (u16(*)[136])sm;   // aliases staging LDS (after final barrier)
  #pragma unroll
  for (int fm=0;fm<2;fm++)
    #pragma unroll
    for (int j=0;j<4;j++){
      float a = 0.f;
      #pragma unroll
      for (int fn=0;fn<4;fn++) a = fmaxf(a, fabsf(acc[fm][fn][j]));
      a = fmaxf(a, __shfl_xor(a,1)); a = fmaxf(a, __shfl_xor(a,2));
      a = fmaxf(a, __shfl_xor(a,4)); a = fmaxf(a, __shfl_xor(a,8));
      a = fmaxf(a, 1e-5f);
      float scale = a / 7.0f;
      int g2 = ((g&1)<<1) | (g>>1);              // sigma: swap bit2<->bit3
      int rowK = wm*32 + fm*16 + g*4  + j;
      int rowV = wm*32 + fm*16 + g2*4 + j;
      #pragma unroll
      for (int fn=0;fn<4;fn++){
        float q = rintf(acc[fm][fn][j] / scale);
        q = fminf(fmaxf(q, -8.f), 7.f);
        _Float16 dq = (_Float16)(q * scale);
        int col = wn*64 + fn*16 + l15;
        if (!isV) sdq[rowK][col] = __builtin_bit_cast(u16, dq);
        else      sdq[col][rowV] = __builtin_bit_cast(u16, dq);
      }
    }
  __syncthreads();

  if (!isV){
    int r = tid>>2, seg = tid&3;
    u16* dst = Out + (size_t)(bm*128 + r)*D_ + bn*128 + seg*32;
    #pragma unroll
    for (int i=0;i<4;i++)
      *(u16x8*)(dst + i*8) = *(const u16x8*)&sdq[r][seg*32 + i*8];
  } else {
    int cc = tid>>2, seg = tid&3;
    int hh = 2*bn + (cc>>6), dd = cc&63, b = bm>>4;
    u16* dst = Out + ((size_t)((b*H_+hh)*HD_ + dd))*T_ + (bm&15)*128 + seg*32;
    #pragma unroll
    for (int i=0;i<4;i++)
      *(u16x8*)(dst + i*8) = *(const u16x8*)&sdq[cc][seg*32 + i*8];
  }
}

// ---------- flash attention, KV-split=2, sigma-permuted V, fp16 partials ----------
// grid 1024 = 8 XCD x 4 bh x (16 qb x 2 split). Wave = 32 q-rows.
// Swapped QK^T (mfma(K,Q)=S^T): lane (c,hi) holds P[q=c][k=crow(r,hi)] in regs.
// PV: A=P in NATURAL slot order; V stored with sigma so B-frags are plain
// rfragT b128 reads. Partial O (fp16) / l (f32) to ws. (No setprio: lockstep
// regime, m190 + round-13 A/B.)
__global__ __launch_bounds__(256, 4)
void attn_kernel(const _Float16* __restrict__ Qp, const u16* __restrict__ Kdq,
                 const u16* __restrict__ Vt, u16* __restrict__ po,
                 float* __restrict__ pl)
{
  __shared__ u16 sK[2][64*64];
  __shared__ u16 sV[2][64*64];
  const int tid = threadIdx.x, l = tid&63, c = l&31, hi = l>>5, w = tid>>6;
  const int dsp = blockIdx.x;
  const int xcd = dsp & 7, slot = dsp >> 3;    // 128 slots per xcd
  const int bh = xcd*4 + (slot>>5);            // 4 bh per xcd
  const int rem = slot & 31;
  const int qb = rem >> 1, sp = rem & 1;       // q-tile, kv-split half
  const int b = bh>>4, h = bh&15;

  // Q B-frags (pre-scaled by 0.125*log2e)
  u16x8 qf[4];
  {
    const u16* qrow = (const u16*)Qp + (size_t)(b*T_ + qb*128 + w*32 + c)*D_ + h*HD_;
    #pragma unroll
    for (int ks=0;ks<4;ks++)
      qf[ks] = *(const u16x8*)(qrow + ks*16 + hi*8);
  }

  f32x16 o0 = {}, o1 = {};
  float lsp = 0.f;

  const u16* Kb = Kdq + (size_t)(b*T_ + sp*1024)*D_ + h*HD_;
  const u16* Vb = Vt  + (size_t)(bh*HD_)*T_ + sp*1024;

  stage_tile<64,4>(Kb, D_, sK[0], tid);
  stage_tile<64,4>(Vb, T_, sV[0], tid);
  __syncthreads();

  for (int kt=0; kt<16; kt++){
    const int cur = kt&1;
    if (kt+1 < 16){
      stage_tile<64,4>(Kb + (size_t)((kt+1)*64)*D_, D_, sK[cur^1], tid);
      stage_tile<64,4>(Vb + (kt+1)*64,              T_, sV[cur^1], tid);
    }
    const u16* sKc = sK[cur];
    const u16* sVc = sV[cur];

    // V B-frags: single b128 per chunk (sigma-permuted layout matches natural P)
    u16x8 vf0[4], vf1[4];
    #pragma unroll
    for (int ch=0; ch<4; ch++){
      vf0[ch] = rfragT(sVc,      c, ch, hi);
      vf1[ch] = rfragT(sVc, 32 + c, ch, hi);
    }

    #pragma unroll
    for (int kb=0;kb<2;kb++){
      f32x16 s = {};
      #pragma unroll
      for (int ks=0;ks<4;ks++){
        u16x8 kf = rfragT(sKc, kb*32 + c, ks, hi);
        s = mfma32_f16(kf, qf[ks], s);
      }
      // p = exp2(S^T); denominator: f32 tree-sum
      float p[16];
      #pragma unroll
      for (int r=0;r<16;r++) p[r] = ex2(s[r]);
      {
        float t0 = (p[0]+p[1]) + (p[2]+p[3]);
        float t1 = (p[4]+p[5]) + (p[6]+p[7]);
        float t2 = (p[8]+p[9]) + (p[10]+p[11]);
        float t3 = (p[12]+p[13]) + (p[14]+p[15]);
        lsp += (t0+t1) + (t2+t3);
      }
      // P -> fp16, natural slot order
      u32x4 pw0 = { pkrtz(p[0],p[1]),  pkrtz(p[2],p[3]),
                    pkrtz(p[4],p[5]),  pkrtz(p[6],p[7]) };
      u32x4 pw1 = { pkrtz(p[8],p[9]),  pkrtz(p[10],p[11]),
                    pkrtz(p[12],p[13]),pkrtz(p[14],p[15]) };
      u16x8 pa0 = __builtin_bit_cast(u16x8, pw0);
      u16x8 pa1 = __builtin_bit_cast(u16x8, pw1);
      o0 = mfma32_f16(pa0, vf0[kb*2+0], o0);
      o0 = mfma32_f16(pa1, vf0[kb*2+1], o0);
      o1 = mfma32_f16(pa0, vf1[kb*2+0], o1);
      o1 = mfma32_f16(pa1, vf1[kb*2+1], o1);
    }
    __syncthreads();
  }

  // partial denominator for q=c (lanes c and c+32 hold disjoint k-subsets)
  float lt = lsp + __shfl_xor(lsp, 32);
  if (hi == 0) pl[(size_t)(sp*32 + bh)*T_ + qb*128 + w*32 + c] = lt;

  u16* pob = po + ((size_t)(sp*32 + bh)*T_ + qb*128 + w*32)*HD_;
  #pragma unroll
  for (int r=0;r<16;r++){
    int crow = (r&3) + 8*(r>>2) + 4*hi;
    pob[crow*HD_ + c]      = __builtin_bit_cast(u16, (_Float16)o0[r]);
    pob[crow*HD_ + 32 + c] = __builtin_bit_cast(u16, (_Float16)o1[r]);
  }
}

// ---------- combine: Ao = (po0 + po1) / (l0 + l1), fp16, XCD-aligned ----------
__global__ __launch_bounds__(256)
void combine_kernel(const u16* __restrict__ po, const float* __restrict__ pl,
                    u16* __restrict__ Ao)
{
  const int dsp = blockIdx.x;
  const int xcd = dsp & 7, slot = dsp >> 3;     // 256 slots per xcd
  const int bh = xcd*4 + (slot>>6);             // 4 bh per xcd
  const int inner = slot & 63;
  int item = inner*256 + threadIdx.x;           // 0..16383
  int d8 = item & 7, t = item >> 3;
  size_t r0 = ((size_t)bh*T_ + t);
  size_t r1 = r0 + (size_t)32*T_;
  h16x8 a = *(const h16x8*)(po + r0*HD_ + d8*8);
  h16x8 bb = *(const h16x8*)(po + r1*HD_ + d8*8);
  float lt = pl[r0] + pl[r1];
  float rl = 1.0f / lt;
  u16x8 o;
  #pragma unroll
  for (int j=0;j<8;j++)
    o[j] = __builtin_bit_cast(u16, (_Float16)(((float)a[j] + (float)bb[j])*rl));
  int b = bh>>4, h = bh&15;
  *(u16x8*)(Ao + ((size_t)(b*T_ + t))*D_ + h*HD_ + d8*8) = o;
}

// ---------- launcher ----------
extern "C" void kernel_launch(void* const* d_in, const int* in_sizes, int n_in,
                              void* d_out, int out_size, void* d_ws, size_t ws_size,
                              hipStream_t stream)
{
  (void)in_sizes; (void)n_in; (void)out_size; (void)ws_size;
  const float* query = (const float*)d_in[0];
  const float* key   = (const float*)d_in[1];
  const float* value = (const float*)d_in[2];
  const float* Wq = (const float*)d_in[3];
  const float* bq = (const float*)d_in[4];
  const float* Wk = (const float*)d_in[5];
  const float* bk = (const float*)d_in[6];
  const float* Wv = (const float*)d_in[7];
  const float* bv = (const float*)d_in[8];
  const float* Wo = (const float*)d_in[9];
  const float* bo = (const float*)d_in[10];
  float* out = (float*)d_out;

  char* p = (char*)d_ws;
  auto take = [&](size_t n){ char* r = p; p += (n + 255) & ~(size_t)255; return r; };
  const size_t big = (size_t)NTOK*D_*2;   // 8 MB
  const size_t wsz = (size_t)D_*D_*2;     // 2 MB

  u16* q_h  = (u16*)take(big);
  u16* wq_h = (u16*)take(wsz);
  u16* wkh  = (u16*)take(wsz);  u16* wkl = (u16*)take(wsz);
  u16* wvh  = (u16*)take(wsz);  u16* wvl = (u16*)take(wsz);
  u16* wo_h = (u16*)take(wsz);
  u16*  Qp  = (u16*)take(big);   // fp16 q-projection (pre-scaled by QSCALE)
  u16*  Kdq = (u16*)take(big);   // fp16 dequantized K (row-major)
  u16*  Vtp = (u16*)take(big);   // fp16 dequantized V^T (sigma-permuted tokens)
  u16*  Ao  = (u16*)take(big);   // fp16 attention output
  u16*  po  = (u16*)take(big*2); // 16 MB fp16 attention partials (64 x 2048 x 64)
  float* pl = (float*)take((size_t)64*T_*4);   // 512 KB partial denominators

  split_all_kernel<<<dim3(NTOK*D_/4/256, 5), 256, 0, stream>>>(
      query, Wq, Wk, Wv, Wo,
      q_h, wq_h, wkh, wkl, wvh, wvl, wo_h);

  gemm1<1><<<dim3(16,32), 256, 0, stream>>>(q_h, wq_h, bq, Qp, QSCALE);

  gemm3_quant_kv<<<dim3(8,32,2), 512, 64*1024, stream>>>(
      key,   wkh, wkl, bk, Kdq,
      value, wvh, wvl, bv, Vtp);

  attn_kernel<<<1024, 256, 0, stream>>>((const _Float16*)Qp, Kdq, Vtp, po, pl);
  combine_kernel<<<2048, 256, 0, stream>>>(po, pl, Ao);

  gemm1<0><<<dim3(16,32), 256, 0, stream>>>(Ao, wo_h, bo, out, 1.0f);
}

// Round 18
// 168.174 us; speedup vs baseline: 1.1335x; 1.0358x over previous
//
#include <hip/hip_runtime.h>

typedef unsigned short u16;
typedef unsigned int u32;
typedef float f32x4 __attribute__((ext_vector_type(4)));
typedef float f32x16 __attribute__((ext_vector_type(16)));
typedef short s16x8 __attribute__((ext_vector_type(8)));
typedef u16 u16x8 __attribute__((ext_vector_type(8)));
typedef u16 u16x4 __attribute__((ext_vector_type(4)));
typedef u32 u32x4 __attribute__((ext_vector_type(4)));
typedef _Float16 h16x8 __attribute__((ext_vector_type(8)));
typedef _Float16 h16x2 __attribute__((ext_vector_type(2)));

#define B_ 2
#define T_ 2048
#define H_ 16
#define D_ 1024
#define HD_ 64
#define NTOK (B_*T_)

// 0.125 (HD^-1/2) * log2(e): folded into Q projection so softmax is exp2-direct.
#define QSCALE 0.18033688011112042f

// ---------- helpers ----------
__device__ __forceinline__ u16 f2b(float f){            // fp32 -> bf16 RNE
  u32 u = __float_as_uint(f);
  return (u16)((u + 0x7fffu + ((u>>16)&1u)) >> 16);
}
__device__ __forceinline__ float b2f(u16 h){ return __uint_as_float(((u32)h)<<16); }

__device__ __forceinline__ void gload_lds16(const u16* g, u16* s){
  __builtin_amdgcn_global_load_lds((const __attribute__((address_space(1))) void*)g,
                                   (__attribute__((address_space(3))) void*)s, 16, 0, 0);
}

// Stage a [ROWS][64] 16-bit tile. LDS linear; XOR swizzle (16B unit u -> u^(r&7))
// applied on the per-lane GLOBAL source address.
template<int ROWS, int WAVES>
__device__ __forceinline__ void stage_tile(const u16* __restrict__ g, size_t ldg,
                                           u16* s, int tid){
  const int w = tid>>6, l = tid&63;
  const int rw = ROWS/WAVES;
  #pragma unroll
  for (int i=0;i<ROWS/(WAVES*8);i++){
    int r0 = w*rw + i*8;
    int r  = r0 + (l>>3);
    int u  = (l&7) ^ (r&7);
    gload_lds16(g + (size_t)r*ldg + (size_t)u*8, s + r0*64);
  }
}

// chunked read from swizzled [*][64] tile: 8 elems at 16-elem chunk ks, half hi.
__device__ __forceinline__ u16x8 rfragT(const u16* s, int r, int ks, int hi){
  int phys = (ks*2 + hi) ^ (r&7);
  return *(const u16x8*)(s + r*64 + phys*8);
}

// BK=32 bf16 tiles [ROWS][32] (8-wave staging): unit v = u^((r>>1)&3).
__device__ __forceinline__ void stage_tile32(const u16* __restrict__ g, size_t ldg,
                                             u16* s, int tid){
  const int w = tid>>6, l = tid&63;
  int r0 = w*16;
  int r  = r0 + (l>>2);
  int v  = (l&3) ^ ((r>>1)&3);
  gload_lds16(g + (size_t)r*ldg + (size_t)v*8, s + r0*32);
}
__device__ __forceinline__ u16x8 read_frag32(const u16* s, int r, int l){
  int phys = (l>>4) ^ ((r>>1)&3);
  return *(const u16x8*)(s + r*32 + phys*8);
}

__device__ __forceinline__ f32x4 mfma16_bf16(u16x8 a, u16x8 b, f32x4 c){
  return __builtin_amdgcn_mfma_f32_16x16x32_bf16(
      __builtin_bit_cast(s16x8,a), __builtin_bit_cast(s16x8,b), c, 0,0,0);
}
__device__ __forceinline__ f32x16 mfma32_f16(u16x8 a, u16x8 b, f32x16 c){
  return __builtin_amdgcn_mfma_f32_32x32x16_f16(
      __builtin_bit_cast(h16x8,a), __builtin_bit_cast(h16x8,b), c, 0,0,0);
}

__device__ __forceinline__ float ex2(float x){
#if __has_builtin(__builtin_amdgcn_exp2f)
  return __builtin_amdgcn_exp2f(x);
#else
  return exp2f(x);
#endif
}
__device__ __forceinline__ u32 pk2(float a, float b){   // two f32 -> packed f16x2 (RNE)
  u16 x = __builtin_bit_cast(u16, (_Float16)a);
  u16 y = __builtin_bit_cast(u16, (_Float16)b);
  return (u32)x | ((u32)y<<16);
}
__device__ __forceinline__ u32 pkrtz(float a, float b){ // packed cvt (v_cvt_pkrtz_f16_f32)
#if __has_builtin(__builtin_amdgcn_cvt_pkrtz)
  auto r = __builtin_amdgcn_cvt_pkrtz(a, b);   // __fp16 ext_vector(2)
  return __builtin_bit_cast(u32, r);
#else
  return pk2(a, b);
#endif
}

// ---------- split kernel: q (fp16) + 4 weight matrices ----------
__device__ __forceinline__ void split_bf4(const float* in, u16* hi, u16* lo, int i){
  f32x4 v = ((const f32x4*)in)[i];
  u16x4 h, lw;
  #pragma unroll
  for (int j=0;j<4;j++){
    u16 hb = f2b(v[j]);
    h[j] = hb;
    lw[j] = f2b(v[j] - b2f(hb));   // exact residual, then RNE
  }
  ((u16x4*)hi)[i] = h;
  ((u16x4*)lo)[i] = lw;
}
__device__ __forceinline__ void split_h4(const float* in, u16* out, int i){
  f32x4 v = ((const f32x4*)in)[i];
  u16x4 o;
  #pragma unroll
  for (int j=0;j<4;j++){
    _Float16 t = (_Float16)v[j];
    o[j] = __builtin_bit_cast(u16, t);
  }
  ((u16x4*)out)[i] = o;
}

__global__ void split_all_kernel(const float* __restrict__ q,
                                 const float* __restrict__ wq, const float* __restrict__ wk,
                                 const float* __restrict__ wv, const float* __restrict__ wo,
                                 u16* __restrict__ qh,
                                 u16* __restrict__ wqh, u16* __restrict__ wkh, u16* __restrict__ wkl,
                                 u16* __restrict__ wvh, u16* __restrict__ wvl, u16* __restrict__ woh){
  int i = blockIdx.x*256 + threadIdx.x;
  int which = blockIdx.y;
  if (which==0){ split_h4(q, qh, i); return; }
  if (i >= D_*D_/4) return;
  if (which==1)      split_h4 (wq, wqh, i);
  else if (which==2) split_bf4(wk, wkh, wkl, i);
  else if (which==3) split_bf4(wv, wvh, wvl, i);
  else               split_h4 (wo, woh, i);
}

// ---------- fp16 1-term GEMM, 32x32 MFMA: C = (A @ W^T + bias) * oscale ----------
// BM=128, BN=64, BK=64, 4 waves (wave 64x32), dbuf 2-phase, 48 KB LDS ->
// 2 blocks/CU (grid 512). Grid (bm, bn) with bm FASTEST: XCD = bm%8 ->
// A panels XCD-local (fetched once); small W dup (8 MB) is the cheap side.
template<int F16OUT>
__global__ __launch_bounds__(256)
void gemm1(const u16* __restrict__ Ah, const u16* __restrict__ Wh,
           const float* __restrict__ bias, void* __restrict__ Cout, float oscale)
{
  __shared__ u16 sA[2][128*64];
  __shared__ u16 sW[2][64*64];
  const int tid = threadIdx.x, l = tid&63, c = l&31, hi = l>>5, w = tid>>6;
  const int wm = w>>1, wn = w&1;
  const int bm = blockIdx.x, bn = blockIdx.y;  // (32,16): XCD = bm%8
  const u16* A0 = Ah + (size_t)bm*128*D_;
  const u16* W0 = Wh + (size_t)bn*64*D_;
  f32x16 acc[2] = {};   // [mb] (single nb)

  stage_tile<128,4>(A0, D_, sA[0], tid);
  stage_tile<64 ,4>(W0, D_, sW[0], tid);
  __syncthreads();
  for (int t=0; t<D_/64; ++t){
    const int cur = t&1;
    if (t+1 < D_/64){
      stage_tile<128,4>(A0 + (t+1)*64, D_, sA[cur^1], tid);
      stage_tile<64 ,4>(W0 + (t+1)*64, D_, sW[cur^1], tid);
    }
    #pragma unroll
    for (int kc=0;kc<4;kc++){
      u16x8 af[2], wf;
      af[0] = rfragT(sA[cur], wm*64 +      c, kc, hi);
      af[1] = rfragT(sA[cur], wm*64 + 32 + c, kc, hi);
      wf    = rfragT(sW[cur], wn*32 +      c, kc, hi);
      #pragma unroll
      for (int mb=0;mb<2;mb++)
        acc[mb] = mfma32_f16(af[mb], wf, acc[mb]);
    }
    __syncthreads();
  }

  {
    int col = bn*64 + wn*32 + c;
    float bv = bias[col];
    #pragma unroll
    for (int mb=0;mb<2;mb++){
      #pragma unroll
      for (int r=0;r<16;r++){
        int row = bm*128 + wm*64 + mb*32 + (r&3) + 8*(r>>2) + 4*hi;
        float v = (acc[mb][r] + bv) * oscale;
        if constexpr (F16OUT){
          ((_Float16*)Cout)[(size_t)row*D_ + col] = (_Float16)v;
        } else {
          ((float*)Cout)[(size_t)row*D_ + col] = v;
        }
      }
    }
  }
}

// ---------- 3-term split GEMM + fused INT4 quant-dequant (R15 exact) ----------
// A staged as RAW F32 via gload_lds, split to (Ah,Al) in-register after the
// LDS read. 16x16 MFMA, 512 threads/8 waves, BM=BN=128, BK=32, dbuf.
// Grid (bm, bn, z) with bm FASTEST: XCD = bm%8 -> the big f32 A panels are
// XCD-local (R17 lesson: bn-fastest duplicated A 8x -> 135 MB fetch).
// z=0 -> K row-major; z=1 -> V transposed with sigma (g2 = swap bit2<->bit3).
__global__ __launch_bounds__(512)
void gemm3_quant_kv(const float* __restrict__ kA, const u16* __restrict__ kWh,
                    const u16* __restrict__ kWl, const float* __restrict__ kbias,
                    u16* __restrict__ kOut,
                    const float* __restrict__ vA, const u16* __restrict__ vWh,
                    const u16* __restrict__ vWl, const float* __restrict__ vbias,
                    u16* __restrict__ vOut)
{
  extern __shared__ u16 sm[];
  const int tid = threadIdx.x, l = tid&63, w = tid>>6, l15 = l&15, g = l>>4;
  const int wm = w>>1, wn = w&1;
  const int bm = blockIdx.x, bn = blockIdx.y;   // (32, 8): XCD = bm%8
  const bool isV = blockIdx.z != 0;
  const float* Af = isV ? vA : kA;
  const u16* Wh = isV ? vWh : kWh;
  const u16* Wl = isV ? vWl : kWl;
  const float* bias = isV ? vbias : kbias;
  u16* Out = isV ? vOut : kOut;

  const u16* A0u = (const u16*)(Af + (size_t)bm*128*D_);   // f32 rows as u16, ldg=2048
  const u16* W0 = Wh + (size_t)bn*128*D_;
  const u16* W1 = Wl + (size_t)bn*128*D_;
  // per buffer: A-f32 [128][32]f32 = 8192 u16, Wh [128][32] = 4096, Wl = 4096
  constexpr int BUF = 16384;
  f32x4 acc[2][4] = {};

  auto stage = [&](int buf, int t){
    u16* base = sm + buf*BUF;
    stage_tile<128,8>(A0u + t*64, 2048, base, tid);   // f32 tile, 128B rows
    stage_tile32(W0 + t*32, D_, base +  8192, tid);
    stage_tile32(W1 + t*32, D_, base + 12288, tid);
  };
  stage(0,0);
  __syncthreads();
  for (int t=0; t<D_/32; ++t){
    const int cur = t&1;
    if (t+1 < D_/32) stage(cur^1, t+1);
    const u16* base = sm + cur*BUF;
    // A frags: read f32, split in-register (hi=trunc16, lo=RNE residual)
    u16x8 ahh[2], ahl[2];
    #pragma unroll
    for (int fm=0;fm<2;fm++){
      int r = wm*32 + fm*16 + l15;
      int rx = r&7;
      const u16* row = base + r*64;
      f32x4 x0 = *(const f32x4*)(row + (((g*2  )^rx)*8));
      f32x4 x1 = *(const f32x4*)(row + (((g*2+1)^rx)*8));
      u16x8 hh, ll;
      #pragma unroll
      for (int j=0;j<4;j++){
        u32 b0 = __float_as_uint(x0[j]);
        hh[j]   = (u16)(b0>>16);
        ll[j]   = f2b(x0[j] - __uint_as_float(b0 & 0xffff0000u));
        u32 b1 = __float_as_uint(x1[j]);
        hh[j+4] = (u16)(b1>>16);
        ll[j+4] = f2b(x1[j] - __uint_as_float(b1 & 0xffff0000u));
      }
      ahh[fm] = hh; ahl[fm] = ll;
    }
    u16x8 whh[4], whl[4];
    #pragma unroll
    for (int fn=0;fn<4;fn++){
      whh[fn] = read_frag32(base +  8192, wn*64+fn*16+l15, l);
      whl[fn] = read_frag32(base + 12288, wn*64+fn*16+l15, l);
    }
    #pragma unroll
    for (int fm=0;fm<2;fm++)
      #pragma unroll
      for (int fn=0;fn<4;fn++){
        acc[fm][fn] = mfma16_bf16(ahh[fm], whh[fn], acc[fm][fn]);
        acc[fm][fn] = mfma16_bf16(ahh[fm], whl[fn], acc[fm][fn]);
        acc[fm][fn] = mfma16_bf16(ahl[fm], whh[fn], acc[fm][fn]);
      }
    __syncthreads();
  }

  // bias
  #pragma unroll
  for (int fn=0;fn<4;fn++){
    float bv = bias[bn*128 + wn*64 + fn*16 + l15];
    #pragma unroll
    for (int fm=0;fm<2;fm++)
      #pragma unroll
      for (int j=0;j<4;j++) acc[fm][fn][j] += bv;
  }

  // quant-dequant: wave's 64 cols = exactly one head -> per-row amax
  u16 (*sdq)[136] = (u16(*)[136])sm;   // aliases staging LDS (after final barrier)
  #pragma unroll
  for (int fm=0;fm<2;fm++)
    #pragma unroll
    for (int j=0;j<4;j++){
      float a = 0.f;
      #pragma unroll
      for (int fn=0;fn<4;fn++) a = fmaxf(a, fabsf(acc[fm][fn][j]));
      a = fmaxf(a, __shfl_xor(a,1)); a = fmaxf(a, __shfl_xor(a,2));
      a = fmaxf(a, __shfl_xor(a,4)); a = fmaxf(a, __shfl_xor(a,8));
      a = fmaxf(a, 1e-5f);
      float scale = a / 7.0f;
      int g2 = ((g&1)<<1) | (g>>1);              // sigma: swap bit2<->bit3
      int rowK = wm*32 + fm*16 + g*4  + j;
      int rowV = wm*32 + fm*16 + g2*4 + j;
      #pragma unroll
      for (int fn=0;fn<4;fn++){
        float q = rintf(acc[fm][fn][j] / scale);
        q = fminf(fmaxf(q, -8.f), 7.f);
        _Float16 dq = (_Float16)(q * scale);
        int col = wn*64 + fn*16 + l15;
        if (!isV) sdq[rowK][col] = __builtin_bit_cast(u16, dq);
        else      sdq[col][rowV] = __builtin_bit_cast(u16, dq);
      }
    }
  __syncthreads();

  if (!isV){
    int r = tid>>2, seg = tid&3;
    u16* dst = Out + (size_t)(bm*128 + r)*D_ + bn*128 + seg*32;
    #pragma unroll
    for (int i=0;i<4;i++)
      *(u16x8*)(dst + i*8) = *(const u16x8*)&sdq[r][seg*32 + i*8];
  } else {
    int cc = tid>>2, seg = tid&3;
    int hh = 2*bn + (cc>>6), dd = cc&63, b = bm>>4;
    u16* dst = Out + ((size_t)((b*H_+hh)*HD_ + dd))*T_ + (bm&15)*128 + seg*32;
    #pragma unroll
    for (int i=0;i<4;i++)
      *(u16x8*)(dst + i*8) = *(const u16x8*)&sdq[cc][seg*32 + i*8];
  }
}

// ---------- flash attention, KV-split=2, sigma-permuted V, fp16 partials ----------
// grid 1024 = 8 XCD x 4 bh x (16 qb x 2 split). Wave = 32 q-rows.
// Swapped QK^T (mfma(K,Q)=S^T): lane (c,hi) holds P[q=c][k=crow(r,hi)] in regs.
// PV: A=P in NATURAL slot order; V stored with sigma so B-frags are plain
// rfragT b128 reads. Partial O (fp16) / l (f32) to ws. (No setprio: lockstep
// regime, m190 + round-13 A/B.)
__global__ __launch_bounds__(256, 4)
void attn_kernel(const _Float16* __restrict__ Qp, const u16* __restrict__ Kdq,
                 const u16* __restrict__ Vt, u16* __restrict__ po,
                 float* __restrict__ pl)
{
  __shared__ u16 sK[2][64*64];
  __shared__ u16 sV[2][64*64];
  const int tid = threadIdx.x, l = tid&63, c = l&31, hi = l>>5, w = tid>>6;
  const int dsp = blockIdx.x;
  const int xcd = dsp & 7, slot = dsp >> 3;    // 128 slots per xcd
  const int bh = xcd*4 + (slot>>5);            // 4 bh per xcd
  const int rem = slot & 31;
  const int qb = rem >> 1, sp = rem & 1;       // q-tile, kv-split half
  const int b = bh>>4, h = bh&15;

  // Q B-frags (pre-scaled by 0.125*log2e)
  u16x8 qf[4];
  {
    const u16* qrow = (const u16*)Qp + (size_t)(b*T_ + qb*128 + w*32 + c)*D_ + h*HD_;
    #pragma unroll
    for (int ks=0;ks<4;ks++)
      qf[ks] = *(const u16x8*)(qrow + ks*16 + hi*8);
  }

  f32x16 o0 = {}, o1 = {};
  float lsp = 0.f;

  const u16* Kb = Kdq + (size_t)(b*T_ + sp*1024)*D_ + h*HD_;
  const u16* Vb = Vt  + (size_t)(bh*HD_)*T_ + sp*1024;

  stage_tile<64,4>(Kb, D_, sK[0], tid);
  stage_tile<64,4>(Vb, T_, sV[0], tid);
  __syncthreads();

  for (int kt=0; kt<16; kt++){
    const int cur = kt&1;
    if (kt+1 < 16){
      stage_tile<64,4>(Kb + (size_t)((kt+1)*64)*D_, D_, sK[cur^1], tid);
      stage_tile<64,4>(Vb + (kt+1)*64,              T_, sV[cur^1], tid);
    }
    const u16* sKc = sK[cur];
    const u16* sVc = sV[cur];

    // V B-frags: single b128 per chunk (sigma-permuted layout matches natural P)
    u16x8 vf0[4], vf1[4];
    #pragma unroll
    for (int ch=0; ch<4; ch++){
      vf0[ch] = rfragT(sVc,      c, ch, hi);
      vf1[ch] = rfragT(sVc, 32 + c, ch, hi);
    }

    #pragma unroll
    for (int kb=0;kb<2;kb++){
      f32x16 s = {};
      #pragma unroll
      for (int ks=0;ks<4;ks++){
        u16x8 kf = rfragT(sKc, kb*32 + c, ks, hi);
        s = mfma32_f16(kf, qf[ks], s);
      }
      // p = exp2(S^T); denominator: f32 tree-sum
      float p[16];
      #pragma unroll
      for (int r=0;r<16;r++) p[r] = ex2(s[r]);
      {
        float t0 = (p[0]+p[1]) + (p[2]+p[3]);
        float t1 = (p[4]+p[5]) + (p[6]+p[7]);
        float t2 = (p[8]+p[9]) + (p[10]+p[11]);
        float t3 = (p[12]+p[13]) + (p[14]+p[15]);
        lsp += (t0+t1) + (t2+t3);
      }
      // P -> fp16, natural slot order
      u32x4 pw0 = { pkrtz(p[0],p[1]),  pkrtz(p[2],p[3]),
                    pkrtz(p[4],p[5]),  pkrtz(p[6],p[7]) };
      u32x4 pw1 = { pkrtz(p[8],p[9]),  pkrtz(p[10],p[11]),
                    pkrtz(p[12],p[13]),pkrtz(p[14],p[15]) };
      u16x8 pa0 = __builtin_bit_cast(u16x8, pw0);
      u16x8 pa1 = __builtin_bit_cast(u16x8, pw1);
      o0 = mfma32_f16(pa0, vf0[kb*2+0], o0);
      o0 = mfma32_f16(pa1, vf0[kb*2+1], o0);
      o1 = mfma32_f16(pa0, vf1[kb*2+0], o1);
      o1 = mfma32_f16(pa1, vf1[kb*2+1], o1);
    }
    __syncthreads();
  }

  // partial denominator for q=c (lanes c and c+32 hold disjoint k-subsets)
  float lt = lsp + __shfl_xor(lsp, 32);
  if (hi == 0) pl[(size_t)(sp*32 + bh)*T_ + qb*128 + w*32 + c] = lt;

  u16* pob = po + ((size_t)(sp*32 + bh)*T_ + qb*128 + w*32)*HD_;
  #pragma unroll
  for (int r=0;r<16;r++){
    int crow = (r&3) + 8*(r>>2) + 4*hi;
    pob[crow*HD_ + c]      = __builtin_bit_cast(u16, (_Float16)o0[r]);
    pob[crow*HD_ + 32 + c] = __builtin_bit_cast(u16, (_Float16)o1[r]);
  }
}

// ---------- combine: Ao = (po0 + po1) / (l0 + l1), fp16, XCD-aligned ----------
__global__ __launch_bounds__(256)
void combine_kernel(const u16* __restrict__ po, const float* __restrict__ pl,
                    u16* __restrict__ Ao)
{
  const int dsp = blockIdx.x;
  const int xcd = dsp & 7, slot = dsp >> 3;     // 256 slots per xcd
  const int bh = xcd*4 + (slot>>6);             // 4 bh per xcd
  const int inner = slot & 63;
  int item = inner*256 + threadIdx.x;           // 0..16383
  int d8 = item & 7, t = item >> 3;
  size_t r0 = ((size_t)bh*T_ + t);
  size_t r1 = r0 + (size_t)32*T_;
  h16x8 a = *(const h16x8*)(po + r0*HD_ + d8*8);
  h16x8 bb = *(const h16x8*)(po + r1*HD_ + d8*8);
  float lt = pl[r0] + pl[r1];
  float rl = 1.0f / lt;
  u16x8 o;
  #pragma unroll
  for (int j=0;j<8;j++)
    o[j] = __builtin_bit_cast(u16, (_Float16)(((float)a[j] + (float)bb[j])*rl));
  int b = bh>>4, h = bh&15;
  *(u16x8*)(Ao + ((size_t)(b*T_ + t))*D_ + h*HD_ + d8*8) = o;
}

// ---------- launcher ----------
extern "C" void kernel_launch(void* const* d_in, const int* in_sizes, int n_in,
                              void* d_out, int out_size, void* d_ws, size_t ws_size,
                              hipStream_t stream)
{
  (void)in_sizes; (void)n_in; (void)out_size; (void)ws_size;
  const float* query = (const float*)d_in[0];
  const float* key   = (const float*)d_in[1];
  const float* value = (const float*)d_in[2];
  const float* Wq = (const float*)d_in[3];
  const float* bq = (const float*)d_in[4];
  const float* Wk = (const float*)d_in[5];
  const float* bk = (const float*)d_in[6];
  const float* Wv = (const float*)d_in[7];
  const float* bv = (const float*)d_in[8];
  const float* Wo = (const float*)d_in[9];
  const float* bo = (const float*)d_in[10];
  float* out = (float*)d_out;

  char* p = (char*)d_ws;
  auto take = [&](size_t n){ char* r = p; p += (n + 255) & ~(size_t)255; return r; };
  const size_t big = (size_t)NTOK*D_*2;   // 8 MB
  const size_t wsz = (size_t)D_*D_*2;     // 2 MB

  u16* q_h  = (u16*)take(big);
  u16* wq_h = (u16*)take(wsz);
  u16* wkh  = (u16*)take(wsz);  u16* wkl = (u16*)take(wsz);
  u16* wvh  = (u16*)take(wsz);  u16* wvl = (u16*)take(wsz);
  u16* wo_h = (u16*)take(wsz);
  u16*  Qp  = (u16*)take(big);   // fp16 q-projection (pre-scaled by QSCALE)
  u16*  Kdq = (u16*)take(big);   // fp16 dequantized K (row-major)
  u16*  Vtp = (u16*)take(big);   // fp16 dequantized V^T (sigma-permuted tokens)
  u16*  Ao  = (u16*)take(big);   // fp16 attention output
  u16*  po  = (u16*)take(big*2); // 16 MB fp16 attention partials (64 x 2048 x 64)
  float* pl = (float*)take((size_t)64*T_*4);   // 512 KB partial denominators

  split_all_kernel<<<dim3(NTOK*D_/4/256, 5), 256, 0, stream>>>(
      query, Wq, Wk, Wv, Wo,
      q_h, wq_h, wkh, wkl, wvh, wvl, wo_h);

  gemm1<1><<<dim3(32,16), 256, 0, stream>>>(q_h, wq_h, bq, Qp, QSCALE);

  gemm3_quant_kv<<<dim3(32,8,2), 512, 64*1024, stream>>>(
      key,   wkh, wkl, bk, Kdq,
      value, wvh, wvl, bv, Vtp);

  attn_kernel<<<1024, 256, 0, stream>>>((const _Float16*)Qp, Kdq, Vtp, po, pl);
  combine_kernel<<<2048, 256, 0, stream>>>(po, pl, Ao);

  gemm1<0><<<dim3(32,16), 256, 0, stream>>>(Ao, wo_h, bo, out, 1.0f);
}

// Round 19
// 164.049 us; speedup vs baseline: 1.1620x; 1.0251x over previous
//
#include <hip/hip_runtime.h>

typedef unsigned short u16;
typedef unsigned int u32;
typedef float f32x4 __attribute__((ext_vector_type(4)));
typedef float f32x16 __attribute__((ext_vector_type(16)));
typedef short s16x8 __attribute__((ext_vector_type(8)));
typedef u16 u16x8 __attribute__((ext_vector_type(8)));
typedef u16 u16x4 __attribute__((ext_vector_type(4)));
typedef u32 u32x4 __attribute__((ext_vector_type(4)));
typedef _Float16 h16x8 __attribute__((ext_vector_type(8)));
typedef _Float16 h16x2 __attribute__((ext_vector_type(2)));

#define B_ 2
#define T_ 2048
#define H_ 16
#define D_ 1024
#define HD_ 64
#define NTOK (B_*T_)

// 0.125 (HD^-1/2) * log2(e): folded into Q projection so softmax is exp2-direct.
#define QSCALE 0.18033688011112042f

// ---------- helpers ----------
__device__ __forceinline__ u16 f2b(float f){            // fp32 -> bf16 RNE
  u32 u = __float_as_uint(f);
  return (u16)((u + 0x7fffu + ((u>>16)&1u)) >> 16);
}
__device__ __forceinline__ float b2f(u16 h){ return __uint_as_float(((u32)h)<<16); }

// pack hi16 of two f32 bit-patterns into one u32 (v_perm_b32)
__device__ __forceinline__ u32 hi16pair(u32 b0, u32 b1){
#if __has_builtin(__builtin_amdgcn_perm)
  return __builtin_amdgcn_perm(b1, b0, 0x07060302u);
#else
  return (b0 >> 16) | (b1 & 0xffff0000u);
#endif
}

__device__ __forceinline__ void gload_lds16(const u16* g, u16* s){
  __builtin_amdgcn_global_load_lds((const __attribute__((address_space(1))) void*)g,
                                   (__attribute__((address_space(3))) void*)s, 16, 0, 0);
}

// Stage a [ROWS][64] 16-bit tile. LDS linear; XOR swizzle (16B unit u -> u^(r&7))
// applied on the per-lane GLOBAL source address.
template<int ROWS, int WAVES>
__device__ __forceinline__ void stage_tile(const u16* __restrict__ g, size_t ldg,
                                           u16* s, int tid){
  const int w = tid>>6, l = tid&63;
  const int rw = ROWS/WAVES;
  #pragma unroll
  for (int i=0;i<ROWS/(WAVES*8);i++){
    int r0 = w*rw + i*8;
    int r  = r0 + (l>>3);
    int u  = (l&7) ^ (r&7);
    gload_lds16(g + (size_t)r*ldg + (size_t)u*8, s + r0*64);
  }
}

// chunked read from swizzled [*][64] tile: 8 elems at 16-elem chunk ks, half hi.
__device__ __forceinline__ u16x8 rfragT(const u16* s, int r, int ks, int hi){
  int phys = (ks*2 + hi) ^ (r&7);
  return *(const u16x8*)(s + r*64 + phys*8);
}

// BK=32 bf16 tiles [ROWS][32] (8-wave staging): unit v = u^((r>>1)&3).
__device__ __forceinline__ void stage_tile32(const u16* __restrict__ g, size_t ldg,
                                             u16* s, int tid){
  const int w = tid>>6, l = tid&63;
  int r0 = w*16;
  int r  = r0 + (l>>2);
  int v  = (l&3) ^ ((r>>1)&3);
  gload_lds16(g + (size_t)r*ldg + (size_t)v*8, s + r0*32);
}
__device__ __forceinline__ u16x8 read_frag32(const u16* s, int r, int l){
  int phys = (l>>4) ^ ((r>>1)&3);
  return *(const u16x8*)(s + r*32 + phys*8);
}

__device__ __forceinline__ f32x4 mfma16_bf16(u16x8 a, u16x8 b, f32x4 c){
  return __builtin_amdgcn_mfma_f32_16x16x32_bf16(
      __builtin_bit_cast(s16x8,a), __builtin_bit_cast(s16x8,b), c, 0,0,0);
}
__device__ __forceinline__ f32x16 mfma32_f16(u16x8 a, u16x8 b, f32x16 c){
  return __builtin_amdgcn_mfma_f32_32x32x16_f16(
      __builtin_bit_cast(h16x8,a), __builtin_bit_cast(h16x8,b), c, 0,0,0);
}

__device__ __forceinline__ float ex2(float x){
#if __has_builtin(__builtin_amdgcn_exp2f)
  return __builtin_amdgcn_exp2f(x);
#else
  return exp2f(x);
#endif
}
__device__ __forceinline__ u32 pk2(float a, float b){   // two f32 -> packed f16x2 (RNE)
  u16 x = __builtin_bit_cast(u16, (_Float16)a);
  u16 y = __builtin_bit_cast(u16, (_Float16)b);
  return (u32)x | ((u32)y<<16);
}
__device__ __forceinline__ u32 pkrtz(float a, float b){ // packed cvt (v_cvt_pkrtz_f16_f32)
#if __has_builtin(__builtin_amdgcn_cvt_pkrtz)
  auto r = __builtin_amdgcn_cvt_pkrtz(a, b);   // __fp16 ext_vector(2)
  return __builtin_bit_cast(u32, r);
#else
  return pk2(a, b);
#endif
}

// ---------- split kernel: q (fp16) + 4 weight matrices ----------
__device__ __forceinline__ void split_bf4(const float* in, u16* hi, u16* lo, int i){
  f32x4 v = ((const f32x4*)in)[i];
  u16x4 h, lw;
  #pragma unroll
  for (int j=0;j<4;j++){
    u16 hb = f2b(v[j]);
    h[j] = hb;
    lw[j] = f2b(v[j] - b2f(hb));   // exact residual, then RNE
  }
  ((u16x4*)hi)[i] = h;
  ((u16x4*)lo)[i] = lw;
}
__device__ __forceinline__ void split_h4(const float* in, u16* out, int i){
  f32x4 v = ((const f32x4*)in)[i];
  u16x4 o;
  #pragma unroll
  for (int j=0;j<4;j++){
    _Float16 t = (_Float16)v[j];
    o[j] = __builtin_bit_cast(u16, t);
  }
  ((u16x4*)out)[i] = o;
}

__global__ void split_all_kernel(const float* __restrict__ q,
                                 const float* __restrict__ wq, const float* __restrict__ wk,
                                 const float* __restrict__ wv, const float* __restrict__ wo,
                                 u16* __restrict__ qh,
                                 u16* __restrict__ wqh, u16* __restrict__ wkh, u16* __restrict__ wkl,
                                 u16* __restrict__ wvh, u16* __restrict__ wvl, u16* __restrict__ woh){
  int i = blockIdx.x*256 + threadIdx.x;
  int which = blockIdx.y;
  if (which==0){ split_h4(q, qh, i); return; }
  if (i >= D_*D_/4) return;
  if (which==1)      split_h4 (wq, wqh, i);
  else if (which==2) split_bf4(wk, wkh, wkl, i);
  else if (which==3) split_bf4(wv, wvh, wvl, i);
  else               split_h4 (wo, woh, i);
}

// ---------- fp16 1-term GEMM, 32x32 MFMA: C = (A @ W^T + bias) * oscale ----------
// BM=128, BN=64, BK=64, 4 waves (wave 64x32), dbuf 2-phase, 48 KB LDS ->
// 2 blocks/CU (grid 512). Grid (bm, bn) with bm FASTEST: A panels XCD-local.
template<int F16OUT>
__global__ __launch_bounds__(256)
void gemm1(const u16* __restrict__ Ah, const u16* __restrict__ Wh,
           const float* __restrict__ bias, void* __restrict__ Cout, float oscale)
{
  __shared__ u16 sA[2][128*64];
  __shared__ u16 sW[2][64*64];
  const int tid = threadIdx.x, l = tid&63, c = l&31, hi = l>>5, w = tid>>6;
  const int wm = w>>1, wn = w&1;
  const int bm = blockIdx.x, bn = blockIdx.y;  // (32,16): XCD = bm%8
  const u16* A0 = Ah + (size_t)bm*128*D_;
  const u16* W0 = Wh + (size_t)bn*64*D_;
  f32x16 acc[2] = {};   // [mb] (single nb)

  stage_tile<128,4>(A0, D_, sA[0], tid);
  stage_tile<64 ,4>(W0, D_, sW[0], tid);
  __syncthreads();
  for (int t=0; t<D_/64; ++t){
    const int cur = t&1;
    if (t+1 < D_/64){
      stage_tile<128,4>(A0 + (t+1)*64, D_, sA[cur^1], tid);
      stage_tile<64 ,4>(W0 + (t+1)*64, D_, sW[cur^1], tid);
    }
    #pragma unroll
    for (int kc=0;kc<4;kc++){
      u16x8 af[2], wf;
      af[0] = rfragT(sA[cur], wm*64 +      c, kc, hi);
      af[1] = rfragT(sA[cur], wm*64 + 32 + c, kc, hi);
      wf    = rfragT(sW[cur], wn*32 +      c, kc, hi);
      #pragma unroll
      for (int mb=0;mb<2;mb++)
        acc[mb] = mfma32_f16(af[mb], wf, acc[mb]);
    }
    __syncthreads();
  }

  {
    int col = bn*64 + wn*32 + c;
    float bv = bias[col];
    #pragma unroll
    for (int mb=0;mb<2;mb++){
      #pragma unroll
      for (int r=0;r<16;r++){
        int row = bm*128 + wm*64 + mb*32 + (r&3) + 8*(r>>2) + 4*hi;
        float v = (acc[mb][r] + bv) * oscale;
        if constexpr (F16OUT){
          ((_Float16*)Cout)[(size_t)row*D_ + col] = (_Float16)v;
        } else {
          ((float*)Cout)[(size_t)row*D_ + col] = v;
        }
      }
    }
  }
}

// ---------- 3-term split GEMM + fused INT4 quant-dequant ----------
// A staged as RAW F32 via gload_lds, split to (Ah,Al) in-register with
// v_perm_b32 pair-packing: hi-pair = 1 perm, lo = sub + trunc-pair perm
// (truncation error 2^-17-relative -- invisible vs quant bins). ~24 VALU
// per fragment-pair vs 48 in R18. 16x16 MFMA, 512 threads/8 waves,
// BM=BN=128, BK=32, dbuf. Grid (bm, bn, z), bm fastest: A panels XCD-local.
// z=0 -> K row-major; z=1 -> V transposed with sigma (g2 = swap bit2<->bit3).
__global__ __launch_bounds__(512)
void gemm3_quant_kv(const float* __restrict__ kA, const u16* __restrict__ kWh,
                    const u16* __restrict__ kWl, const float* __restrict__ kbias,
                    u16* __restrict__ kOut,
                    const float* __restrict__ vA, const u16* __restrict__ vWh,
                    const u16* __restrict__ vWl, const float* __restrict__ vbias,
                    u16* __restrict__ vOut)
{
  extern __shared__ u16 sm[];
  const int tid = threadIdx.x, l = tid&63, w = tid>>6, l15 = l&15, g = l>>4;
  const int wm = w>>1, wn = w&1;
  const int bm = blockIdx.x, bn = blockIdx.y;   // (32, 8): XCD = bm%8
  const bool isV = blockIdx.z != 0;
  const float* Af = isV ? vA : kA;
  const u16* Wh = isV ? vWh : kWh;
  const u16* Wl = isV ? vWl : kWl;
  const float* bias = isV ? vbias : kbias;
  u16* Out = isV ? vOut : kOut;

  const u16* A0u = (const u16*)(Af + (size_t)bm*128*D_);   // f32 rows as u16, ldg=2048
  const u16* W0 = Wh + (size_t)bn*128*D_;
  const u16* W1 = Wl + (size_t)bn*128*D_;
  // per buffer: A-f32 [128][32]f32 = 8192 u16, Wh [128][32] = 4096, Wl = 4096
  constexpr int BUF = 16384;
  f32x4 acc[2][4] = {};

  auto stage = [&](int buf, int t){
    u16* base = sm + buf*BUF;
    stage_tile<128,8>(A0u + t*64, 2048, base, tid);   // f32 tile, 128B rows
    stage_tile32(W0 + t*32, D_, base +  8192, tid);
    stage_tile32(W1 + t*32, D_, base + 12288, tid);
  };
  stage(0,0);
  __syncthreads();
  for (int t=0; t<D_/32; ++t){
    const int cur = t&1;
    if (t+1 < D_/32) stage(cur^1, t+1);
    const u16* base = sm + cur*BUF;
    // A frags: read f32, split in-register (hi = trunc-top-16 via v_perm pair,
    // lo = trunc of exact residual via v_perm pair)
    u16x8 ahh[2], ahl[2];
    #pragma unroll
    for (int fm=0;fm<2;fm++){
      int r = wm*32 + fm*16 + l15;
      int rx = r&7;
      const u16* row = base + r*64;
      f32x4 x0 = *(const f32x4*)(row + (((g*2  )^rx)*8));
      f32x4 x1 = *(const f32x4*)(row + (((g*2+1)^rx)*8));
      u32x4 hw, lw;
      #pragma unroll
      for (int p=0;p<2;p++){
        u32 b0 = __float_as_uint(x0[2*p]);
        u32 b1 = __float_as_uint(x0[2*p+1]);
        hw[p] = hi16pair(b0, b1);
        float r0 = x0[2*p]   - __uint_as_float(b0 & 0xffff0000u);
        float r1 = x0[2*p+1] - __uint_as_float(b1 & 0xffff0000u);
        lw[p] = hi16pair(__float_as_uint(r0), __float_as_uint(r1));
      }
      #pragma unroll
      for (int p=0;p<2;p++){
        u32 b0 = __float_as_uint(x1[2*p]);
        u32 b1 = __float_as_uint(x1[2*p+1]);
        hw[2+p] = hi16pair(b0, b1);
        float r0 = x1[2*p]   - __uint_as_float(b0 & 0xffff0000u);
        float r1 = x1[2*p+1] - __uint_as_float(b1 & 0xffff0000u);
        lw[2+p] = hi16pair(__float_as_uint(r0), __float_as_uint(r1));
      }
      ahh[fm] = __builtin_bit_cast(u16x8, hw);
      ahl[fm] = __builtin_bit_cast(u16x8, lw);
    }
    u16x8 whh[4], whl[4];
    #pragma unroll
    for (int fn=0;fn<4;fn++){
      whh[fn] = read_frag32(base +  8192, wn*64+fn*16+l15, l);
      whl[fn] = read_frag32(base + 12288, wn*64+fn*16+l15, l);
    }
    #pragma unroll
    for (int fm=0;fm<2;fm++)
      #pragma unroll
      for (int fn=0;fn<4;fn++){
        acc[fm][fn] = mfma16_bf16(ahh[fm], whh[fn], acc[fm][fn]);
        acc[fm][fn] = mfma16_bf16(ahh[fm], whl[fn], acc[fm][fn]);
        acc[fm][fn] = mfma16_bf16(ahl[fm], whh[fn], acc[fm][fn]);
      }
    __syncthreads();
  }

  // bias
  #pragma unroll
  for (int fn=0;fn<4;fn++){
    float bv = bias[bn*128 + wn*64 + fn*16 + l15];
    #pragma unroll
    for (int fm=0;fm<2;fm++)
      #pragma unroll
      for (int j=0;j<4;j++) acc[fm][fn][j] += bv;
  }

  // quant-dequant: wave's 64 cols = exactly one head -> per-row amax
  u16 (*sdq)[136] = (u16(*)[136])sm;   // aliases staging LDS (after final barrier)
  #pragma unroll
  for (int fm=0;fm<2;fm++)
    #pragma unroll
    for (int j=0;j<4;j++){
      float a = 0.f;
      #pragma unroll
      for (int fn=0;fn<4;fn++) a = fmaxf(a, fabsf(acc[fm][fn][j]));
      a = fmaxf(a, __shfl_xor(a,1)); a = fmaxf(a, __shfl_xor(a,2));
      a = fmaxf(a, __shfl_xor(a,4)); a = fmaxf(a, __shfl_xor(a,8));
      a = fmaxf(a, 1e-5f);
      float scale = a / 7.0f;
      int g2 = ((g&1)<<1) | (g>>1);              // sigma: swap bit2<->bit3
      int rowK = wm*32 + fm*16 + g*4  + j;
      int rowV = wm*32 + fm*16 + g2*4 + j;
      #pragma unroll
      for (int fn=0;fn<4;fn++){
        float q = rintf(acc[fm][fn][j] / scale);
        q = fminf(fmaxf(q, -8.f), 7.f);
        _Float16 dq = (_Float16)(q * scale);
        int col = wn*64 + fn*16 + l15;
        if (!isV) sdq[rowK][col] = __builtin_bit_cast(u16, dq);
        else      sdq[col][rowV] = __builtin_bit_cast(u16, dq);
      }
    }
  __syncthreads();

  if (!isV){
    int r = tid>>2, seg = tid&3;
    u16* dst = Out + (size_t)(bm*128 + r)*D_ + bn*128 + seg*32;
    #pragma unroll
    for (int i=0;i<4;i++)
      *(u16x8*)(dst + i*8) = *(const u16x8*)&sdq[r][seg*32 + i*8];
  } else {
    int cc = tid>>2, seg = tid&3;
    int hh = 2*bn + (cc>>6), dd = cc&63, b = bm>>4;
    u16* dst = Out + ((size_t)((b*H_+hh)*HD_ + dd))*T_ + (bm&15)*128 + seg*32;
    #pragma unroll
    for (int i=0;i<4;i++)
      *(u16x8*)(dst + i*8) = *(const u16x8*)&sdq[cc][seg*32 + i*8];
  }
}

// ---------- flash attention, KV-split=2, sigma-permuted V, fp16 partials ----------
// grid 1024 = 8 XCD x 4 bh x (16 qb x 2 split). Wave = 32 q-rows.
// Swapped QK^T (mfma(K,Q)=S^T): lane (c,hi) holds P[q=c][k=crow(r,hi)] in regs.
// PV: A=P in NATURAL slot order; V stored with sigma so B-frags are plain
// rfragT b128 reads. Partial O (fp16) / l (f32) to ws. (No setprio: lockstep
// regime, m190 + round-13 A/B.)
__global__ __launch_bounds__(256, 4)
void attn_kernel(const _Float16* __restrict__ Qp, const u16* __restrict__ Kdq,
                 const u16* __restrict__ Vt, u16* __restrict__ po,
                 float* __restrict__ pl)
{
  __shared__ u16 sK[2][64*64];
  __shared__ u16 sV[2][64*64];
  const int tid = threadIdx.x, l = tid&63, c = l&31, hi = l>>5, w = tid>>6;
  const int dsp = blockIdx.x;
  const int xcd = dsp & 7, slot = dsp >> 3;    // 128 slots per xcd
  const int bh = xcd*4 + (slot>>5);            // 4 bh per xcd
  const int rem = slot & 31;
  const int qb = rem >> 1, sp = rem & 1;       // q-tile, kv-split half
  const int b = bh>>4, h = bh&15;

  // Q B-frags (pre-scaled by 0.125*log2e)
  u16x8 qf[4];
  {
    const u16* qrow = (const u16*)Qp + (size_t)(b*T_ + qb*128 + w*32 + c)*D_ + h*HD_;
    #pragma unroll
    for (int ks=0;ks<4;ks++)
      qf[ks] = *(const u16x8*)(qrow + ks*16 + hi*8);
  }

  f32x16 o0 = {}, o1 = {};
  float lsp = 0.f;

  const u16* Kb = Kdq + (size_t)(b*T_ + sp*1024)*D_ + h*HD_;
  const u16* Vb = Vt  + (size_t)(bh*HD_)*T_ + sp*1024;

  stage_tile<64,4>(Kb, D_, sK[0], tid);
  stage_tile<64,4>(Vb, T_, sV[0], tid);
  __syncthreads();

  for (int kt=0; kt<16; kt++){
    const int cur = kt&1;
    if (kt+1 < 16){
      stage_tile<64,4>(Kb + (size_t)((kt+1)*64)*D_, D_, sK[cur^1], tid);
      stage_tile<64,4>(Vb + (kt+1)*64,              T_, sV[cur^1], tid);
    }
    const u16* sKc = sK[cur];
    const u16* sVc = sV[cur];

    // V B-frags: single b128 per chunk (sigma-permuted layout matches natural P)
    u16x8 vf0[4], vf1[4];
    #pragma unroll
    for (int ch=0; ch<4; ch++){
      vf0[ch] = rfragT(sVc,      c, ch, hi);
      vf1[ch] = rfragT(sVc, 32 + c, ch, hi);
    }

    #pragma unroll
    for (int kb=0;kb<2;kb++){
      f32x16 s = {};
      #pragma unroll
      for (int ks=0;ks<4;ks++){
        u16x8 kf = rfragT(sKc, kb*32 + c, ks, hi);
        s = mfma32_f16(kf, qf[ks], s);
      }
      // p = exp2(S^T); denominator: f32 tree-sum
      float p[16];
      #pragma unroll
      for (int r=0;r<16;r++) p[r] = ex2(s[r]);
      {
        float t0 = (p[0]+p[1]) + (p[2]+p[3]);
        float t1 = (p[4]+p[5]) + (p[6]+p[7]);
        float t2 = (p[8]+p[9]) + (p[10]+p[11]);
        float t3 = (p[12]+p[13]) + (p[14]+p[15]);
        lsp += (t0+t1) + (t2+t3);
      }
      // P -> fp16, natural slot order
      u32x4 pw0 = { pkrtz(p[0],p[1]),  pkrtz(p[2],p[3]),
                    pkrtz(p[4],p[5]),  pkrtz(p[6],p[7]) };
      u32x4 pw1 = { pkrtz(p[8],p[9]),  pkrtz(p[10],p[11]),
                    pkrtz(p[12],p[13]),pkrtz(p[14],p[15]) };
      u16x8 pa0 = __builtin_bit_cast(u16x8, pw0);
      u16x8 pa1 = __builtin_bit_cast(u16x8, pw1);
      o0 = mfma32_f16(pa0, vf0[kb*2+0], o0);
      o0 = mfma32_f16(pa1, vf0[kb*2+1], o0);
      o1 = mfma32_f16(pa0, vf1[kb*2+0], o1);
      o1 = mfma32_f16(pa1, vf1[kb*2+1], o1);
    }
    __syncthreads();
  }

  // partial denominator for q=c (lanes c and c+32 hold disjoint k-subsets)
  float lt = lsp + __shfl_xor(lsp, 32);
  if (hi == 0) pl[(size_t)(sp*32 + bh)*T_ + qb*128 + w*32 + c] = lt;

  u16* pob = po + ((size_t)(sp*32 + bh)*T_ + qb*128 + w*32)*HD_;
  #pragma unroll
  for (int r=0;r<16;r++){
    int crow = (r&3) + 8*(r>>2) + 4*hi;
    pob[crow*HD_ + c]      = __builtin_bit_cast(u16, (_Float16)o0[r]);
    pob[crow*HD_ + 32 + c] = __builtin_bit_cast(u16, (_Float16)o1[r]);
  }
}

// ---------- combine: Ao = (po0 + po1) / (l0 + l1), fp16, XCD-aligned ----------
__global__ __launch_bounds__(256)
void combine_kernel(const u16* __restrict__ po, const float* __restrict__ pl,
                    u16* __restrict__ Ao)
{
  const int dsp = blockIdx.x;
  const int xcd = dsp & 7, slot = dsp >> 3;     // 256 slots per xcd
  const int bh = xcd*4 + (slot>>6);             // 4 bh per xcd
  const int inner = slot & 63;
  int item = inner*256 + threadIdx.x;           // 0..16383
  int d8 = item & 7, t = item >> 3;
  size_t r0 = ((size_t)bh*T_ + t);
  size_t r1 = r0 + (size_t)32*T_;
  h16x8 a = *(const h16x8*)(po + r0*HD_ + d8*8);
  h16x8 bb = *(const h16x8*)(po + r1*HD_ + d8*8);
  float lt = pl[r0] + pl[r1];
  float rl = 1.0f / lt;
  u16x8 o;
  #pragma unroll
  for (int j=0;j<8;j++)
    o[j] = __builtin_bit_cast(u16, (_Float16)(((float)a[j] + (float)bb[j])*rl));
  int b = bh>>4, h = bh&15;
  *(u16x8*)(Ao + ((size_t)(b*T_ + t))*D_ + h*HD_ + d8*8) = o;
}

// ---------- launcher ----------
extern "C" void kernel_launch(void* const* d_in, const int* in_sizes, int n_in,
                              void* d_out, int out_size, void* d_ws, size_t ws_size,
                              hipStream_t stream)
{
  (void)in_sizes; (void)n_in; (void)out_size; (void)ws_size;
  const float* query = (const float*)d_in[0];
  const float* key   = (const float*)d_in[1];
  const float* value = (const float*)d_in[2];
  const float* Wq = (const float*)d_in[3];
  const float* bq = (const float*)d_in[4];
  const float* Wk = (const float*)d_in[5];
  const float* bk = (const float*)d_in[6];
  const float* Wv = (const float*)d_in[7];
  const float* bv = (const float*)d_in[8];
  const float* Wo = (const float*)d_in[9];
  const float* bo = (const float*)d_in[10];
  float* out = (float*)d_out;

  char* p = (char*)d_ws;
  auto take = [&](size_t n){ char* r = p; p += (n + 255) & ~(size_t)255; return r; };
  const size_t big = (size_t)NTOK*D_*2;   // 8 MB
  const size_t wsz = (size_t)D_*D_*2;     // 2 MB

  u16* q_h  = (u16*)take(big);
  u16* wq_h = (u16*)take(wsz);
  u16* wkh  = (u16*)take(wsz);  u16* wkl = (u16*)take(wsz);
  u16* wvh  = (u16*)take(wsz);  u16* wvl = (u16*)take(wsz);
  u16* wo_h = (u16*)take(wsz);
  u16*  Qp  = (u16*)take(big);   // fp16 q-projection (pre-scaled by QSCALE)
  u16*  Kdq = (u16*)take(big);   // fp16 dequantized K (row-major)
  u16*  Vtp = (u16*)take(big);   // fp16 dequantized V^T (sigma-permuted tokens)
  u16*  Ao  = (u16*)take(big);   // fp16 attention output
  u16*  po  = (u16*)take(big*2); // 16 MB fp16 attention partials (64 x 2048 x 64)
  float* pl = (float*)take((size_t)64*T_*4);   // 512 KB partial denominators

  split_all_kernel<<<dim3(NTOK*D_/4/256, 5), 256, 0, stream>>>(
      query, Wq, Wk, Wv, Wo,
      q_h, wq_h, wkh, wkl, wvh, wvl, wo_h);

  gemm1<1><<<dim3(32,16), 256, 0, stream>>>(q_h, wq_h, bq, Qp, QSCALE);

  gemm3_quant_kv<<<dim3(32,8,2), 512, 64*1024, stream>>>(
      key,   wkh, wkl, bk, Kdq,
      value, wvh, wvl, bv, Vtp);

  attn_kernel<<<1024, 256, 0, stream>>>((const _Float16*)Qp, Kdq, Vtp, po, pl);
  combine_kernel<<<2048, 256, 0, stream>>>(po, pl, Ao);

  gemm1<0><<<dim3(32,16), 256, 0, stream>>>(Ao, wo_h, bo, out, 1.0f);
}